// Round 2
// baseline (748.712 us; speedup 1.0000x reference)
//
#include <hip/hip_runtime.h>
#include <cstdint>
#include <math.h>

#define BATCH    65536
#define HIS_LEN  5
#define KIND_LEN 10
#define SB       64    // samples per block
#define NTH      512   // threads per block (8 waves); 8 threads per sample

typedef float v2f __attribute__((ext_vector_type(2)));
__device__ __forceinline__ v2f mk2(float a, float b){ v2f r; r.x=a; r.y=b; return r; }

// ---- ws layout (fp32 element offsets) — unchanged ----
#define OFF_WC1 0        // 12288
#define OFF_AB1 12288    // 64
#define OFF_W2T 12352    // 2048  [o*32+p]
#define OFF_AB2 14400    // 32
#define OFF_W3  14432    // 32
#define OFF_AB3 14464    // 1
#define OFF_M1  14720    // 26624 [128 o][4 q][52] sliced
#define OFF_MB1 41344    // 128
#define OFF_M2T 41472    // 8192  [o*64+p]
#define OFF_MB2 49664    // 64
#define OFF_M3T 49728    // 2048  [o*32+p]
#define OFF_MB3 51776    // 32
#define OFF_M4  51808    // 32
#define OFF_MB4 51840    // 1
#define PREP_N  51586

// LDS float layout:
//   [0,6144)      two 768-f4 chunk buffers (history keeps both halves resident)
//   [6144,8450)   persistent PF (AB1,W2T,AB2,W3,AB3 | MB2 | MB3,M4,MB4)
//   [8450,10498)  tp: 4096 bf16 = 64 outputs x 64 samples (t2 + ab1)
#define PFF   6144
#define W2TF4 1552      // (PFF+64)/4
#define LDSF  10498

typedef const float* fp;

// lane q owns feature elements idx = 8r + 2q + e (r<11, e<2) of each 88-vec
__global__ void din_prep(fp aw1, fp ab1, fp aw2, fp ab2, fp aw3, fp ab3,
                         fp m1,  fp mb1, fp m2,  fp mb2, fp m3,  fp mb3,
                         fp m4,  fp mb4, float* __restrict__ ws){
  int i = blockIdx.x*blockDim.x + threadIdx.x;
  int j = i;
  if(j < 12288){ // act_w1 combined+sliced+padded
    int o = j/192, t = j%192;
    int h = t/96; int tt = t - 96*h;
    int q = tt/24, d = tt - 24*q;
    float v = 0.f;
    if(d < 22){
      int idx = 8*(d>>1) + 2*q + (d&1);
      v = (h==0) ? (aw1[o*264+idx] + aw1[o*264+88+idx])
                 : (aw1[o*264+176+idx] - aw1[o*264+88+idx]);
    }
    ws[OFF_WC1 + j] = v; return;
  } j -= 12288;
  if(j < 64){ ws[OFF_AB1 + j] = ab1[j]; return; } j -= 64;
  if(j < 2048){ int o=j/32, p=j%32; ws[OFF_W2T + j] = aw2[p*64 + o]; return; } j -= 2048;
  if(j < 32){ ws[OFF_AB2 + j] = ab2[j]; return; } j -= 32;
  if(j < 32){ ws[OFF_W3  + j] = aw3[j]; return; } j -= 32;
  if(j < 1){ ws[OFF_AB3] = ab3[0]; return; } j -= 1;
  if(j < 26624){ // mlp_w1 sliced: [ex8 | i2part22 | poolpart22] per q
    int o = j/208, r = j%208;
    int q = r/52, t = r-52*q;
    int src;
    if(t<8){ int E = (q==0)?0:(8+8*q); src = E + t; }
    else if(t<30){ int d=t-8; int idx = 8*(d>>1)+2*q+(d&1);
                   src = (idx<8) ? (8+idx) : (32+idx); }
    else { int d=t-30; int idx = 8*(d>>1)+2*q+(d&1); src = 120+idx; }
    ws[OFF_M1 + j] = m1[o*208 + src]; return;
  } j -= 26624;
  if(j < 128){ ws[OFF_MB1 + j] = mb1[j]; return; } j -= 128;
  if(j < 8192){ int o=j/64, p=j%64; ws[OFF_M2T + j] = m2[p*128 + o]; return; } j -= 8192;
  if(j < 64){ ws[OFF_MB2 + j] = mb2[j]; return; } j -= 64;
  if(j < 2048){ int o=j/32, p=j%32; ws[OFF_M3T + j] = m3[p*64 + o]; return; } j -= 2048;
  if(j < 32){ ws[OFF_MB3 + j] = mb3[j]; return; } j -= 32;
  if(j < 32){ ws[OFF_M4  + j] = m4[j];  return; } j -= 32;
  if(j < 1){ ws[OFF_MB4] = mb4[0]; return; }
}

__device__ __forceinline__ float bsum4(float v){
  v += __shfl_xor(v, 1);
  v += __shfl_xor(v, 2);
  return v;
}
__device__ __forceinline__ unsigned short f2bf(float f){
  unsigned int u = __float_as_uint(f);
  return (unsigned short)((u + 0x7fffu + ((u>>16)&1u)) >> 16);
}
__device__ __forceinline__ float bf2f(unsigned short s){
  return __uint_as_float(((unsigned int)s) << 16);
}

// async global->LDS staging (dest is wave-uniform base + lane*size; all our
// staging dests are lane-linear within each wave)
__device__ __forceinline__ void ldst16(void* l, const void* g){
  __builtin_amdgcn_global_load_lds(
      (const __attribute__((address_space(1))) unsigned int*)(uintptr_t)g,
      (__attribute__((address_space(3))) unsigned int*)(uintptr_t)l, 16, 0, 0);
}
__device__ __forceinline__ void ldst4(void* l, const void* g){
  __builtin_amdgcn_global_load_lds(
      (const __attribute__((address_space(1))) unsigned int*)(uintptr_t)g,
      (__attribute__((address_space(3))) unsigned int*)(uintptr_t)l, 4, 0, 0);
}

__device__ __forceinline__ void gather_slice(const float2* __restrict__ itemp,
                                             const float2* __restrict__ kindp,
                                             int item_idx, const int* __restrict__ kidx,
                                             int q, v2f* f){
  float2 v = itemp[item_idx*4 + q];
  f[0] = mk2(v.x, v.y);
  #pragma unroll
  for(int r=0;r<KIND_LEN;r++){
    int ki = kidx[r];
    float2 w = kindp[ki*4 + q];
    bool m = (ki!=0);
    f[1+r] = m ? mk2(w.x, w.y) : mk2(0.f, 0.f);
  }
}

#define PKF(acc, a, b, vv) do{ (acc) = __builtin_elementwise_fma(mk2((a),(b)), (vv), (acc)); }while(0)

// act-unit body for one step's feature slice i1v over rows [o0,o1), h2v +=
__device__ __forceinline__ void act_rows(int o0, int o1, int q, int wid,
    const float* ls, const float4* ls4, const unsigned short* tp,
    const v2f* i1v, v2f* h2v){
  #pragma unroll 1
  for(int oo=o0; oo<o1; oo++){
    const float4* wr = ls4 + oo*24 + 6*q;
    float t2b = bf2f(tp[oo*64 + wid]);
    v2f aA = mk2(0.f,0.f), aB = mk2(0.f,0.f);
    #pragma unroll
    for(int k=0;k<5;k++){
      float4 w = wr[k];
      PKF(aA, w.x, w.y, i1v[2*k]);
      PKF(aB, w.z, w.w, i1v[2*k+1]);
    }
    { float4 w = wr[5]; PKF(aA, w.x, w.y, i1v[10]); }
    float h = bsum4((aA.x+aB.x)+(aA.y+aB.y)) + t2b;
    h = fmaxf(h, 0.f);
    v2f hh = mk2(h, h);
    float4 wa = ls4[W2TF4 + oo*8 + 2*q];
    float4 wb = ls4[W2TF4 + 1 + oo*8 + 2*q];
    PKF(h2v[0], wa.x, wa.y, hh);
    PKF(h2v[1], wa.z, wa.w, hh);
    PKF(h2v[2], wb.x, wb.y, hh);
    PKF(h2v[3], wb.z, wb.w, hh);
  }
}

__device__ __forceinline__ float act_tail(int q, const float* ls, const v2f* h2v){
  float scp = 0.f;
  #pragma unroll
  for(int jj=0;jj<4;jj++){
    float hx = fmaxf(h2v[jj].x + ls[PFF+2112+8*q+2*jj],   0.f);
    float hy = fmaxf(h2v[jj].y + ls[PFF+2112+8*q+2*jj+1], 0.f);
    scp += ls[PFF+2144+8*q+2*jj]*hx + ls[PFF+2144+8*q+2*jj+1]*hy;
  }
  return bsum4(scp) + ls[PFF+2176];
}

__device__ __forceinline__ void mlp_stage(int c, int tid, float* ls, float4* ls4,
                                          const float* ws, const float4* ws4){
  int buf = (c&1)*768;
  int j = tid;   // 544 f4: M1S 416 | M2T 128
  const float4* src = (j<416) ? (ws4 + 3680 + c*416 + j)
                              : (ws4 + 10368 + c*128 + (j-416));
  ldst16(ls4 + buf + j, src);
  if(tid < 32) ldst16(ls4 + buf + 512 + tid, ws4 + 10368 + c*128 + 96 + tid);
  if(tid < 8)  ldst4(ls + buf*4 + 2176 + tid, ws + OFF_MB1 + c*8 + tid);
}

// 512 threads; 64 samples/block; 8 threads/sample: q=lane&3 K-split, e=bit2
// splits outputs (phase A / MLP) or history steps (pair passes).
__global__ void __launch_bounds__(NTH, 6)
din_main(const int* __restrict__ userid, const int* __restrict__ itemid,
         const int* __restrict__ age,    const int* __restrict__ gen,
         const int* __restrict__ occ,    const int* __restrict__ item_kind,
         const int* __restrict__ his_id, const int* __restrict__ his_kind,
         const float2* __restrict__ user_emb, const float2* __restrict__ item_emb,
         const float2* __restrict__ age_emb,  const float2* __restrict__ gen_emb,
         const float2* __restrict__ occ_emb,  const float2* __restrict__ kind_emb,
         const float* __restrict__ ws, float* __restrict__ out){
  const int tid  = threadIdx.x;
  const int q    = tid & 3;
  const int e    = (tid >> 2) & 1;
  const int sl   = (tid & 63) >> 3;
  const int wv   = __builtin_amdgcn_readfirstlane(tid >> 6);
  const int wid  = wv*8 + sl;                 // sample-in-block 0..63
  const int b    = blockIdx.x*SB + wid;

  __shared__ __align__(16) float ls[LDSF];
  float4* ls4 = (float4*)ls;
  const float* wsc = ws;
  const float4* ws4 = (const float4*)ws;
  unsigned short* tp = (unsigned short*)(ls + PFF + 2306);

  // ---- initial async staging: PF block (2306 f) + phase-A weight chunks ----
  #pragma unroll
  for(int k=0;k<4;k++){ int j = k*NTH + tid; ldst4(ls + PFF + j, wsc + 12288 + j); }
  { int j = 4*NTH + tid;
    if(j < 2306){
      const float* src = (j<2177) ? (wsc + 12288 + j)
                       : (j<2241) ? (wsc + 49664 + (j-2177))
                                  : (wsc + 51776 + (j-2241));
      ldst4(ls + PFF + j, src);
    } }
  #pragma unroll
  for(int k=0;k<3;k++){
    int j = k*NTH + tid;                 // < 1536
    int r = j/24, d4 = j - r*24;
    ldst16(ls4 + j, ws4 + r*48 + 24 + d4);   // h=1 half (wC - wB)
  }

  // ---- i2 slice (overlaps staging latency) ----
  v2f i2v[11];
  gather_slice(item_emb, kind_emb, itemid[b], item_kind + b*KIND_LEN, q, i2v);

  __syncthreads();   // staging drained

  // ---- phase A: t2+ab1 -> bf16 tp; e splits output rows ----
  #pragma unroll 1
  for(int i=0;i<32;i++){
    int oo = 2*i + e;
    const float4* wr = ls4 + oo*24 + 6*q;
    v2f aA = mk2(0.f,0.f), aB = mk2(0.f,0.f);
    #pragma unroll
    for(int k=0;k<5;k++){
      float4 w = wr[k];
      PKF(aA, w.x, w.y, i2v[2*k]);
      PKF(aB, w.z, w.w, i2v[2*k+1]);
    }
    { float4 w = wr[5]; PKF(aA, w.x, w.y, i2v[10]); }
    float s = bsum4((aA.x+aB.x)+(aA.y+aB.y));
    if(q==0) tp[oo*64 + wid] = f2bf(s + ls[PFF + oo]);
  }
  __syncthreads();   // A reads + tp writes done
  #pragma unroll
  for(int k=0;k<3;k++){
    int j = k*NTH + tid;
    int r = j/24, d4 = j - r*24;
    ldst16(ls4 + j, ws4 + r*48 + d4);        // h=0 half (wA + wB), both chunks
  }
  __syncthreads();   // history weights resident for the rest of history

  // ---- history: passes {0,1}, {2,3} (e = step), {4} (e splits rows) ----
  v2f poolv[11];
  #pragma unroll
  for(int d=0;d<11;d++) poolv[d]=mk2(0.f,0.f);

  #pragma unroll 1
  for(int p=0;p<2;p++){
    int s0 = 2*p;
    v2f i1v[11];
    gather_slice(item_emb, kind_emb, his_id[b*HIS_LEN + s0 + e],
                 his_kind + (b*HIS_LEN + s0 + e)*KIND_LEN, q, i1v);
    v2f h2v[4];
    #pragma unroll
    for(int j=0;j<4;j++) h2v[j] = mk2(0.f,0.f);
    act_rows(0, 64, q, wid, ls, ls4, tp, i1v, h2v);
    float sc = act_tail(q, ls, h2v);
    v2f scv = mk2(sc, sc);
    #pragma unroll
    for(int d=0;d<11;d++){
      v2f tt = i1v[d]*scv;
      poolv[d] = __builtin_elementwise_fma(tt, i1v[d], poolv[d]);
    }
  }
  { // step 4: both e lanes same step, split output rows; reduce h2v over e
    v2f i1v[11];
    gather_slice(item_emb, kind_emb, his_id[b*HIS_LEN + 4],
                 his_kind + (b*HIS_LEN + 4)*KIND_LEN, q, i1v);
    v2f h2v[4];
    #pragma unroll
    for(int j=0;j<4;j++) h2v[j] = mk2(0.f,0.f);
    act_rows(e*32, e*32+32, q, wid, ls, ls4, tp, i1v, h2v);
    #pragma unroll
    for(int j=0;j<4;j++){
      h2v[j].x += __shfl_xor(h2v[j].x, 4);
      h2v[j].y += __shfl_xor(h2v[j].y, 4);
    }
    float sc = act_tail(q, ls, h2v);
    float sce = (e==0) ? sc : 0.f;           // count step 4 once after e-reduce
    v2f scv = mk2(sce, sce);
    #pragma unroll
    for(int d=0;d<11;d++){
      v2f tt = i1v[d]*scv;
      poolv[d] = __builtin_elementwise_fma(tt, i1v[d], poolv[d]);
    }
  }
  // e-reduce pool (combines the paired steps)
  #pragma unroll
  for(int d=0;d<11;d++){
    poolv[d].x += __shfl_xor(poolv[d].x, 4);
    poolv[d].y += __shfl_xor(poolv[d].y, 4);
  }

  // ---- MLP prologue: re-gather i2, extras, h2m (bias on e==0 only) ----
  gather_slice(item_emb, kind_emb, itemid[b], item_kind + b*KIND_LEN, q, i2v);
  v2f exv[4];
  {
    const float2* ep = (q==0)? user_emb : (q==1)? age_emb : (q==2)? gen_emb : occ_emb;
    int ei = (q==0)? userid[b] : (q==1)? age[b] : (q==2)? gen[b] : occ[b];
    #pragma unroll
    for(int k=0;k<4;k++){ float2 v = ep[ei*4+k]; exv[k]=mk2(v.x,v.y); }
  }
  v2f h2m[8];
  #pragma unroll
  for(int j=0;j<8;j++)
    h2m[j] = (e==0) ? mk2(ls[PFF+2177+16*q+2*j], ls[PFF+2177+16*q+2*j+1])
                    : mk2(0.f, 0.f);

  __syncthreads();                  // all waves done reading history bufs
  mlp_stage(0, tid, ls, ls4, wsc, ws4);
  __syncthreads();                  // chunk 0 resident

  // ---- MLP layers 1+2: 16 ping-pong chunks; e splits the 8 outputs ----
  #pragma unroll 1
  for(int c=0;c<16;c++){
    int base = (c&1)*768;
    if(c<15){
      mlp_stage(c+1, tid, ls, ls4, wsc, ws4);
    } else {
      // tail: stage M3T with per-q skew (row 16q+i at f4 q*130+i*8) into buf0
      int j = tid;
      ldst16(ls4 + (j>>7)*130 + (j&127), ws4 + 12432 + j);
    }
    #pragma unroll 1
    for(int ii=0;ii<4;ii++){
      int io = 2*ii + e;
      const float4* wr = ls4 + base + io*52 + 13*q;
      v2f aA = mk2(0.f,0.f), aB = mk2(0.f,0.f);
      { float4 w = wr[0]; PKF(aA, w.x, w.y, exv[0]); PKF(aB, w.z, w.w, exv[1]); }
      { float4 w = wr[1]; PKF(aA, w.x, w.y, exv[2]); PKF(aB, w.z, w.w, exv[3]); }
      #pragma unroll
      for(int k=0;k<5;k++){
        float4 w = wr[2+k];
        PKF(aA, w.x, w.y, i2v[2*k]);
        PKF(aB, w.z, w.w, i2v[2*k+1]);
      }
      { float4 w = wr[7]; PKF(aA, w.x, w.y, i2v[10]); PKF(aB, w.z, w.w, poolv[0]); }
      #pragma unroll
      for(int k=0;k<5;k++){
        float4 w = wr[8+k];
        PKF(aA, w.x, w.y, poolv[2*k+1]);
        PKF(aB, w.z, w.w, poolv[2*k+2]);
      }
      float h = fmaxf(bsum4((aA.x+aB.x)+(aA.y+aB.y)) + ls[base*4 + 2176 + io], 0.f);
      v2f hh = mk2(h, h);
      const float4* w2 = ls4 + base + 416 + io*16 + 4*q;
      #pragma unroll
      for(int k=0;k<4;k++){
        float4 w = w2[k];
        PKF(h2m[2*k],   w.x, w.y, hh);
        PKF(h2m[2*k+1], w.z, w.w, hh);
      }
    }
    __syncthreads();   // joins waves + drains next chunk's (or tail's) loads
  }

  // ---- tail: layers 3+4 (e-reduce h2m, e splits the 16 inputs) ----
  #pragma unroll
  for(int j=0;j<8;j++){
    h2m[j].x += __shfl_xor(h2m[j].x, 4);
    h2m[j].y += __shfl_xor(h2m[j].y, 4);
  }
  float h3p[32];
  #pragma unroll
  for(int j=0;j<32;j++) h3p[j]=0.f;
  #pragma unroll
  for(int ii=0;ii<8;ii++){
    int i = 2*ii + e;
    float hv = e ? h2m[ii].y : h2m[ii].x;
    float v = fmaxf(hv, 0.f);
    const float4* w3 = ls4 + q*130 + i*8;
    #pragma unroll
    for(int j=0;j<8;j++){
      float4 w = w3[j];
      h3p[4*j]+=w.x*v; h3p[4*j+1]+=w.y*v; h3p[4*j+2]+=w.z*v; h3p[4*j+3]+=w.w*v;
    }
  }
  #pragma unroll
  for(int j=0;j<32;j++) h3p[j] += __shfl_xor(h3p[j], 1);
  #pragma unroll
  for(int j=0;j<32;j++) h3p[j] += __shfl_xor(h3p[j], 2);
  #pragma unroll
  for(int j=0;j<32;j++) h3p[j] += __shfl_xor(h3p[j], 4);

  float x = ls[PFF+2305];
  #pragma unroll
  for(int j=0;j<32;j++) x += ls[PFF+2273+j] * fmaxf(h3p[j] + ls[PFF+2241+j], 0.f);

  if((tid&7)==0) out[b] = 1.0f/(1.0f + __expf(-x));
}

extern "C" void kernel_launch(void* const* d_in, const int* in_sizes, int n_in,
                              void* d_out, int out_size, void* d_ws, size_t ws_size,
                              hipStream_t stream){
  const int* userid    = (const int*)d_in[0];
  const int* itemid    = (const int*)d_in[1];
  const int* age       = (const int*)d_in[2];
  const int* gen       = (const int*)d_in[3];
  const int* occ       = (const int*)d_in[4];
  const int* item_kind = (const int*)d_in[5];
  const int* his_id    = (const int*)d_in[6];
  const int* his_kind  = (const int*)d_in[7];
  const float2* user_emb = (const float2*)d_in[8];
  const float2* item_emb = (const float2*)d_in[9];
  const float2* age_emb  = (const float2*)d_in[10];
  const float2* gen_emb  = (const float2*)d_in[11];
  const float2* occ_emb  = (const float2*)d_in[12];
  const float2* kind_emb = (const float2*)d_in[13];
  float* ws = (float*)d_ws;

  din_prep<<<(PREP_N+255)/256, 256, 0, stream>>>(
      (fp)d_in[14], (fp)d_in[15], (fp)d_in[16], (fp)d_in[17], (fp)d_in[18], (fp)d_in[19],
      (fp)d_in[20], (fp)d_in[21], (fp)d_in[22], (fp)d_in[23], (fp)d_in[24], (fp)d_in[25],
      (fp)d_in[26], (fp)d_in[27], ws);

  din_main<<<BATCH/SB, NTH, 0, stream>>>(
      userid, itemid, age, gen, occ, item_kind, his_id, his_kind,
      user_emb, item_emb, age_emb, gen_emb, occ_emb, kind_emb,
      ws, (float*)d_out);
}

// Round 3
// 511.945 us; speedup vs baseline: 1.4625x; 1.4625x over previous
//
#include <hip/hip_runtime.h>
#include <cstdint>
#include <math.h>

#define BATCH    65536
#define HIS_LEN  5
#define KIND_LEN 10
#define SB       128   // samples per block
#define NTH      512   // threads per block (8 waves); 4 threads per sample

typedef float v2f __attribute__((ext_vector_type(2)));
__device__ __forceinline__ v2f mk2(float a, float b){ v2f r; r.x=a; r.y=b; return r; }

// ---- ws layout (fp32 element offsets) — unchanged ----
#define OFF_WC1 0        // 12288  [64 o][2 half][4 q][24]
#define OFF_AB1 12288    // 64
#define OFF_W2T 12352    // 2048  [o*32+p]
#define OFF_AB2 14400    // 32
#define OFF_W3  14432    // 32
#define OFF_AB3 14464    // 1
#define OFF_M1  14720    // 26624 [128 o][4 q][52] sliced
#define OFF_MB1 41344    // 128
#define OFF_M2T 41472    // 8192  [o*64+p]
#define OFF_MB2 49664    // 64
#define OFF_M3T 49728    // 2048  [o*32+p]
#define OFF_MB3 51776    // 32
#define OFF_M4  51808    // 32
#define OFF_MB4 51840    // 1
#define PREP_N  51586

// LDS float layout:
//   [0,6144)      two 768-f4 MLP chunk buffers (+ per-chunk bias slot)
//   [6144,8450)   persistent PF (AB1,W2T,AB2,W3,AB3 | MB2 | MB3,M4,MB4)
//   [8450,12546)  tp: 8192 bf16 = 64 outputs x 128 samples (t2 + ab1)
// phase-A / history WEIGHTS are NOT staged: read direct from global (L2-hot)
#define PFF   6144
#define W2TF4 1552      // (PFF+64)/4
#define LDSF  12546

typedef const float* fp;

// lane q owns feature elements idx = 8r + 2q + e (r<11, e<2) of each 88-vec
__global__ void din_prep(fp aw1, fp ab1, fp aw2, fp ab2, fp aw3, fp ab3,
                         fp m1,  fp mb1, fp m2,  fp mb2, fp m3,  fp mb3,
                         fp m4,  fp mb4, float* __restrict__ ws){
  int i = blockIdx.x*blockDim.x + threadIdx.x;
  int j = i;
  if(j < 12288){ // act_w1 combined+sliced+padded
    int o = j/192, t = j%192;
    int h = t/96; int tt = t - 96*h;
    int q = tt/24, d = tt - 24*q;
    float v = 0.f;
    if(d < 22){
      int idx = 8*(d>>1) + 2*q + (d&1);
      v = (h==0) ? (aw1[o*264+idx] + aw1[o*264+88+idx])
                 : (aw1[o*264+176+idx] - aw1[o*264+88+idx]);
    }
    ws[OFF_WC1 + j] = v; return;
  } j -= 12288;
  if(j < 64){ ws[OFF_AB1 + j] = ab1[j]; return; } j -= 64;
  if(j < 2048){ int o=j/32, p=j%32; ws[OFF_W2T + j] = aw2[p*64 + o]; return; } j -= 2048;
  if(j < 32){ ws[OFF_AB2 + j] = ab2[j]; return; } j -= 32;
  if(j < 32){ ws[OFF_W3  + j] = aw3[j]; return; } j -= 32;
  if(j < 1){ ws[OFF_AB3] = ab3[0]; return; } j -= 1;
  if(j < 26624){ // mlp_w1 sliced: [ex8 | i2part22 | poolpart22] per q
    int o = j/208, r = j%208;
    int q = r/52, t = r-52*q;
    int src;
    if(t<8){ int E = (q==0)?0:(8+8*q); src = E + t; }
    else if(t<30){ int d=t-8; int idx = 8*(d>>1)+2*q+(d&1);
                   src = (idx<8) ? (8+idx) : (32+idx); }
    else { int d=t-30; int idx = 8*(d>>1)+2*q+(d&1); src = 120+idx; }
    ws[OFF_M1 + j] = m1[o*208 + src]; return;
  } j -= 26624;
  if(j < 128){ ws[OFF_MB1 + j] = mb1[j]; return; } j -= 128;
  if(j < 8192){ int o=j/64, p=j%64; ws[OFF_M2T + j] = m2[p*128 + o]; return; } j -= 8192;
  if(j < 64){ ws[OFF_MB2 + j] = mb2[j]; return; } j -= 64;
  if(j < 2048){ int o=j/32, p=j%32; ws[OFF_M3T + j] = m3[p*64 + o]; return; } j -= 2048;
  if(j < 32){ ws[OFF_MB3 + j] = mb3[j]; return; } j -= 32;
  if(j < 32){ ws[OFF_M4  + j] = m4[j];  return; } j -= 32;
  if(j < 1){ ws[OFF_MB4] = mb4[0]; return; }
}

__device__ __forceinline__ float bsum4(float v){
  v += __shfl_xor(v, 1);
  v += __shfl_xor(v, 2);
  return v;
}
__device__ __forceinline__ unsigned short f2bf(float f){
  unsigned int u = __float_as_uint(f);
  return (unsigned short)((u + 0x7fffu + ((u>>16)&1u)) >> 16);
}
__device__ __forceinline__ float bf2f(unsigned short s){
  return __uint_as_float(((unsigned int)s) << 16);
}

// async global->LDS staging (dest wave-uniform base + lane*size; all staging
// dests are lane-linear within each wave)
__device__ __forceinline__ void ldst16(void* l, const void* g){
  __builtin_amdgcn_global_load_lds(
      (const __attribute__((address_space(1))) unsigned int*)(uintptr_t)g,
      (__attribute__((address_space(3))) unsigned int*)(uintptr_t)l, 16, 0, 0);
}
__device__ __forceinline__ void ldst4(void* l, const void* g){
  __builtin_amdgcn_global_load_lds(
      (const __attribute__((address_space(1))) unsigned int*)(uintptr_t)g,
      (__attribute__((address_space(3))) unsigned int*)(uintptr_t)l, 4, 0, 0);
}

__device__ __forceinline__ void gather_slice(const float2* __restrict__ itemp,
                                             const float2* __restrict__ kindp,
                                             int item_idx, const int* __restrict__ kidx,
                                             int q, v2f* f){
  float2 v = itemp[item_idx*4 + q];
  f[0] = mk2(v.x, v.y);
  #pragma unroll
  for(int r=0;r<KIND_LEN;r++){
    int ki = kidx[r];
    float2 w = kindp[ki*4 + q];
    bool m = (ki!=0);
    f[1+r] = m ? mk2(w.x, w.y) : mk2(0.f, 0.f);
  }
}

#define PKF(acc, a, b, vv) do{ (acc) = __builtin_elementwise_fma(mk2((a),(b)), (vv), (acc)); }while(0)

// one history pass over NS steps; act-W1 read DIRECT FROM GLOBAL (L2-hot),
// W2T from persistent LDS, t2 from bf16 tp cache. Shares every weight read
// across the NS steps.
template<int NS>
__device__ __forceinline__ void hist_pass(int b, int s0, int q, int wid,
    const float2* __restrict__ item_emb, const float2* __restrict__ kind_emb,
    const int* __restrict__ his_id, const int* __restrict__ his_kind,
    const float* ls, const float4* ls4, const float4* __restrict__ ws4,
    const unsigned short* tp, v2f* poolv){
  v2f i1v[NS][11];
  #pragma unroll
  for(int t=0;t<NS;t++)
    gather_slice(item_emb, kind_emb, his_id[b*HIS_LEN + s0 + t],
                 his_kind + (b*HIS_LEN + s0 + t)*KIND_LEN, q, i1v[t]);
  v2f h2v[NS][4];
  #pragma unroll
  for(int t=0;t<NS;t++)
    #pragma unroll
    for(int j=0;j<4;j++) h2v[t][j] = mk2(0.f,0.f);

  #pragma unroll 1
  for(int oo=0;oo<64;oo++){
    const float4* wr = ws4 + oo*48 + 6*q;        // h=0 half (wA + wB), global
    float t2b = bf2f(tp[oo*SB + wid]);
    v2f aA[NS], aB[NS];
    #pragma unroll
    for(int t=0;t<NS;t++){ aA[t]=mk2(0.f,0.f); aB[t]=mk2(0.f,0.f); }
    #pragma unroll
    for(int k=0;k<5;k++){
      float4 w = wr[k];
      #pragma unroll
      for(int t=0;t<NS;t++){
        PKF(aA[t], w.x, w.y, i1v[t][2*k]);
        PKF(aB[t], w.z, w.w, i1v[t][2*k+1]);
      }
    }
    { float4 w = wr[5];
      #pragma unroll
      for(int t=0;t<NS;t++) PKF(aA[t], w.x, w.y, i1v[t][10]); }
    float4 wa = ls4[W2TF4 + oo*8 + 2*q];
    float4 wb = ls4[W2TF4 + 1 + oo*8 + 2*q];
    #pragma unroll
    for(int t=0;t<NS;t++){
      float h = bsum4((aA[t].x+aB[t].x)+(aA[t].y+aB[t].y)) + t2b;
      h = fmaxf(h, 0.f);
      v2f hh = mk2(h, h);
      PKF(h2v[t][0], wa.x, wa.y, hh);
      PKF(h2v[t][1], wa.z, wa.w, hh);
      PKF(h2v[t][2], wb.x, wb.y, hh);
      PKF(h2v[t][3], wb.z, wb.w, hh);
    }
  }
  #pragma unroll
  for(int t=0;t<NS;t++){
    float scp = 0.f;
    #pragma unroll
    for(int jj=0;jj<4;jj++){
      float hx = fmaxf(h2v[t][jj].x + ls[PFF+2112+8*q+2*jj],   0.f);
      float hy = fmaxf(h2v[t][jj].y + ls[PFF+2112+8*q+2*jj+1], 0.f);
      scp += ls[PFF+2144+8*q+2*jj]*hx + ls[PFF+2144+8*q+2*jj+1]*hy;
    }
    float sc = bsum4(scp) + ls[PFF+2176];
    v2f scv = mk2(sc, sc);
    #pragma unroll
    for(int d=0;d<11;d++){
      v2f tt = i1v[t][d]*scv;
      poolv[d] = __builtin_elementwise_fma(tt, i1v[t][d], poolv[d]);
    }
  }
}

__device__ __forceinline__ void mlp_stage(int c, int tid, float* ls, float4* ls4,
                                          const float* ws, const float4* ws4){
  int buf = (c&1)*768;
  int j = tid;   // 544 f4: M1S 416 | M2T 128
  const float4* src = (j<416) ? (ws4 + 3680 + c*416 + j)
                              : (ws4 + 10368 + c*128 + (j-416));
  ldst16(ls4 + buf + j, src);
  if(tid < 32) ldst16(ls4 + buf + 512 + tid, ws4 + 10368 + c*128 + 96 + tid);
  if(tid < 8)  ldst4(ls + buf*4 + 2176 + tid, ws + OFF_MB1 + c*8 + tid);
}

// 512 threads; 128 samples/block; quad (q=lane&3) K-splits every dot.
__global__ void __launch_bounds__(NTH, 4)
din_main(const int* __restrict__ userid, const int* __restrict__ itemid,
         const int* __restrict__ age,    const int* __restrict__ gen,
         const int* __restrict__ occ,    const int* __restrict__ item_kind,
         const int* __restrict__ his_id, const int* __restrict__ his_kind,
         const float2* __restrict__ user_emb, const float2* __restrict__ item_emb,
         const float2* __restrict__ age_emb,  const float2* __restrict__ gen_emb,
         const float2* __restrict__ occ_emb,  const float2* __restrict__ kind_emb,
         const float* __restrict__ ws, float* __restrict__ out){
  const int tid  = threadIdx.x;
  const int q    = tid & 3;
  const int sl   = (tid & 63) >> 2;
  const int wv   = __builtin_amdgcn_readfirstlane(tid >> 6);
  const int wid  = wv*16 + sl;                 // sample-in-block 0..127
  const int b    = blockIdx.x*SB + wid;

  __shared__ __align__(16) float ls[LDSF];
  float4* ls4 = (float4*)ls;
  const float* wsc = ws;
  const float4* ws4 = (const float4*)ws;
  unsigned short* tp = (unsigned short*)(ls + PFF + 2306);

  // ---- initial async staging: PF block only (2306 f) ----
  #pragma unroll
  for(int k=0;k<4;k++){ int j = k*NTH + tid; ldst4(ls + PFF + j, wsc + 12288 + j); }
  { int j = 4*NTH + tid;
    if(j < 2306){
      const float* src = (j<2177) ? (wsc + 12288 + j)
                       : (j<2241) ? (wsc + 49664 + (j-2177))
                                  : (wsc + 51776 + (j-2241));
      ldst4(ls + PFF + j, src);
    } }

  // ---- i2 slice (overlaps PF staging latency) ----
  v2f i2v[11];
  gather_slice(item_emb, kind_emb, itemid[b], item_kind + b*KIND_LEN, q, i2v);

  __syncthreads();   // PF resident

  // prefetch MLP chunks 0,1 now — in flight through phaseA + history,
  // drained by the pre-MLP barrier
  mlp_stage(0, tid, ls, ls4, wsc, ws4);
  mlp_stage(1, tid, ls, ls4, wsc, ws4);

  // ---- phase A: t2+ab1 -> bf16 tp (h=1 weights direct from global) ----
  // tp entries are written and later read by the SAME quad -> no barrier.
  #pragma unroll 2
  for(int oo=0;oo<64;oo++){
    const float4* wr = ws4 + oo*48 + 24 + 6*q;
    v2f aA = mk2(0.f,0.f), aB = mk2(0.f,0.f);
    #pragma unroll
    for(int k=0;k<5;k++){
      float4 w = wr[k];
      PKF(aA, w.x, w.y, i2v[2*k]);
      PKF(aB, w.z, w.w, i2v[2*k+1]);
    }
    { float4 w = wr[5]; PKF(aA, w.x, w.y, i2v[10]); }
    float s = bsum4((aA.x+aB.x)+(aA.y+aB.y));
    if(q==0) tp[oo*SB + wid] = f2bf(s + ls[PFF + oo]);
  }

  // ---- history: 3 passes (2+2+1 steps), weights from global, no barriers ----
  v2f poolv[11];
  #pragma unroll
  for(int d=0;d<11;d++) poolv[d]=mk2(0.f,0.f);
  hist_pass<2>(b, 0, q, wid, item_emb, kind_emb, his_id, his_kind, ls, ls4, ws4, tp, poolv);
  hist_pass<2>(b, 2, q, wid, item_emb, kind_emb, his_id, his_kind, ls, ls4, ws4, tp, poolv);
  hist_pass<1>(b, 4, q, wid, item_emb, kind_emb, his_id, his_kind, ls, ls4, ws4, tp, poolv);

  // ---- MLP prologue: re-gather i2 (frees regs during history), extras, h2m ----
  gather_slice(item_emb, kind_emb, itemid[b], item_kind + b*KIND_LEN, q, i2v);
  v2f exv[4];
  {
    const float2* ep = (q==0)? user_emb : (q==1)? age_emb : (q==2)? gen_emb : occ_emb;
    int ei = (q==0)? userid[b] : (q==1)? age[b] : (q==2)? gen[b] : occ[b];
    #pragma unroll
    for(int k=0;k<4;k++){ float2 v = ep[ei*4+k]; exv[k]=mk2(v.x,v.y); }
  }
  v2f h2m[8];
  #pragma unroll
  for(int j=0;j<8;j++) h2m[j] = mk2(ls[PFF+2177+16*q+2*j], ls[PFF+2177+16*q+2*j+1]);

  __syncthreads();   // drains chunk 0,1 loads; aligns waves

  // ---- MLP layers 1+2: 16 chunks, stage(c+2) after each barrier ----
  #pragma unroll 1
  for(int c=0;c<16;c++){
    int base = (c&1)*768;
    #pragma unroll 1
    for(int i=0;i<8;i++){
      const float4* wr = ls4 + base + i*52 + 13*q;
      v2f aA = mk2(0.f,0.f), aB = mk2(0.f,0.f);
      { float4 w = wr[0]; PKF(aA, w.x, w.y, exv[0]); PKF(aB, w.z, w.w, exv[1]); }
      { float4 w = wr[1]; PKF(aA, w.x, w.y, exv[2]); PKF(aB, w.z, w.w, exv[3]); }
      #pragma unroll
      for(int k=0;k<5;k++){
        float4 w = wr[2+k];
        PKF(aA, w.x, w.y, i2v[2*k]);
        PKF(aB, w.z, w.w, i2v[2*k+1]);
      }
      { float4 w = wr[7]; PKF(aA, w.x, w.y, i2v[10]); PKF(aB, w.z, w.w, poolv[0]); }
      #pragma unroll
      for(int k=0;k<5;k++){
        float4 w = wr[8+k];
        PKF(aA, w.x, w.y, poolv[2*k+1]);
        PKF(aB, w.z, w.w, poolv[2*k+2]);
      }
      float h = fmaxf(bsum4((aA.x+aB.x)+(aA.y+aB.y)) + ls[base*4 + 2176 + i], 0.f);
      v2f hh = mk2(h, h);
      const float4* w2 = ls4 + base + 416 + i*16 + 4*q;
      #pragma unroll
      for(int k=0;k<4;k++){
        float4 w = w2[k];
        PKF(h2m[2*k],   w.x, w.y, hh);
        PKF(h2m[2*k+1], w.z, w.w, hh);
      }
    }
    __syncthreads();          // all waves done with buf[c&1]; drains last stage
    if(c < 14){
      mlp_stage(c+2, tid, ls, ls4, wsc, ws4);   // into buf[c&1], 1-chunk ahead
    } else if(c == 14){
      // tail: stage M3T with per-q skew (row 16q+i at f4 q*130+i*8) into buf0
      int j = tid;
      ldst16(ls4 + (j>>7)*130 + (j&127), ws4 + 12432 + j);
    }
  }
  // loop-end barrier of c==15 drained the M3T loads

  // ---- tail: layers 3+4, grouped 8 outputs at a time (no 32-reg array) ----
  float hv[16];
  #pragma unroll
  for(int j=0;j<16;j++) hv[j] = fmaxf((j&1) ? h2m[j>>1].y : h2m[j>>1].x, 0.f);

  float x = ls[PFF+2305];
  #pragma unroll
  for(int g=0;g<4;g++){
    float a[8];
    #pragma unroll
    for(int j=0;j<8;j++) a[j]=0.f;
    #pragma unroll
    for(int i=0;i<16;i++){
      float4 wA = ls4[q*130 + i*8 + 2*g];
      float4 wB = ls4[q*130 + i*8 + 2*g + 1];
      a[0]+=wA.x*hv[i]; a[1]+=wA.y*hv[i]; a[2]+=wA.z*hv[i]; a[3]+=wA.w*hv[i];
      a[4]+=wB.x*hv[i]; a[5]+=wB.y*hv[i]; a[6]+=wB.z*hv[i]; a[7]+=wB.w*hv[i];
    }
    #pragma unroll
    for(int j=0;j<8;j++){ a[j] += __shfl_xor(a[j],1); a[j] += __shfl_xor(a[j],2); }
    #pragma unroll
    for(int j=0;j<8;j++)
      x += ls[PFF+2273+8*g+j] * fmaxf(a[j] + ls[PFF+2241+8*g+j], 0.f);
  }

  if(q==0) out[b] = 1.0f/(1.0f + __expf(-x));
}

extern "C" void kernel_launch(void* const* d_in, const int* in_sizes, int n_in,
                              void* d_out, int out_size, void* d_ws, size_t ws_size,
                              hipStream_t stream){
  const int* userid    = (const int*)d_in[0];
  const int* itemid    = (const int*)d_in[1];
  const int* age       = (const int*)d_in[2];
  const int* gen       = (const int*)d_in[3];
  const int* occ       = (const int*)d_in[4];
  const int* item_kind = (const int*)d_in[5];
  const int* his_id    = (const int*)d_in[6];
  const int* his_kind  = (const int*)d_in[7];
  const float2* user_emb = (const float2*)d_in[8];
  const float2* item_emb = (const float2*)d_in[9];
  const float2* age_emb  = (const float2*)d_in[10];
  const float2* gen_emb  = (const float2*)d_in[11];
  const float2* occ_emb  = (const float2*)d_in[12];
  const float2* kind_emb = (const float2*)d_in[13];
  float* ws = (float*)d_ws;

  din_prep<<<(PREP_N+255)/256, 256, 0, stream>>>(
      (fp)d_in[14], (fp)d_in[15], (fp)d_in[16], (fp)d_in[17], (fp)d_in[18], (fp)d_in[19],
      (fp)d_in[20], (fp)d_in[21], (fp)d_in[22], (fp)d_in[23], (fp)d_in[24], (fp)d_in[25],
      (fp)d_in[26], (fp)d_in[27], ws);

  din_main<<<BATCH/SB, NTH, 0, stream>>>(
      userid, itemid, age, gen, occ, item_kind, his_id, his_kind,
      user_emb, item_emb, age_emb, gen_emb, occ_emb, kind_emb,
      ws, (float*)d_out);
}

// Round 4
// 347.754 us; speedup vs baseline: 2.1530x; 1.4721x over previous
//
#include <hip/hip_runtime.h>
#include <cstdint>
#include <math.h>

#define BATCH    65536
#define HIS_LEN  5
#define KIND_LEN 10
#define SB       128   // samples per block
#define NTH      512   // threads per block (8 waves); 4 threads per sample

typedef float v2f __attribute__((ext_vector_type(2)));
__device__ __forceinline__ v2f mk2(float a, float b){ v2f r; r.x=a; r.y=b; return r; }

// ---- ws layout (fp32 element offsets) — unchanged ----
#define OFF_WC1 0        // 12288  [64 o][2 half][4 q][24]
#define OFF_AB1 12288    // 64
#define OFF_W2T 12352    // 2048  [o*32+p]
#define OFF_AB2 14400    // 32
#define OFF_W3  14432    // 32
#define OFF_AB3 14464    // 1
#define OFF_M1  14720    // 26624 [128 o][4 q][52] sliced
#define OFF_MB1 41344    // 128
#define OFF_M2T 41472    // 8192  [o*64+p]
#define OFF_MB2 49664    // 64
#define OFF_M3T 49728    // 2048  [o*32+p]
#define OFF_MB3 51776    // 32
#define OFF_M4  51808    // 32
#define OFF_MB4 51840    // 1
#define PREP_N  51586

// LDS float layout:
//   f4 [0,1536)      act-w1 h=0 half (wA+wB), row o at f4 o*24   (history)
//   f4 [1536,3072)   act-w1 h=1 half (wC-wB), row o at 1536+o*24 (phase A)
//                    -> after phase A this region becomes the two 768-f4
//                       MLP chunk buffers (and finally the skewed M3T)
//   floats [12288,14594)  persistent PF (AB1,W2T,AB2,W3,AB3 | MB2 | MB3,M4,MB4)
//   floats [14594,18690)  tp: 8192 bf16 = 64 outputs x 128 samples (t2+ab1)
#define PFF   12288
#define W2TF4 3088      // (PFF+64)/4
#define LDSF  18690

typedef const float* fp;

// lane q owns feature elements idx = 8r + 2q + e (r<11, e<2) of each 88-vec
__global__ void din_prep(fp aw1, fp ab1, fp aw2, fp ab2, fp aw3, fp ab3,
                         fp m1,  fp mb1, fp m2,  fp mb2, fp m3,  fp mb3,
                         fp m4,  fp mb4, float* __restrict__ ws){
  int i = blockIdx.x*blockDim.x + threadIdx.x;
  int j = i;
  if(j < 12288){ // act_w1 combined+sliced+padded
    int o = j/192, t = j%192;
    int h = t/96; int tt = t - 96*h;
    int q = tt/24, d = tt - 24*q;
    float v = 0.f;
    if(d < 22){
      int idx = 8*(d>>1) + 2*q + (d&1);
      v = (h==0) ? (aw1[o*264+idx] + aw1[o*264+88+idx])
                 : (aw1[o*264+176+idx] - aw1[o*264+88+idx]);
    }
    ws[OFF_WC1 + j] = v; return;
  } j -= 12288;
  if(j < 64){ ws[OFF_AB1 + j] = ab1[j]; return; } j -= 64;
  if(j < 2048){ int o=j/32, p=j%32; ws[OFF_W2T + j] = aw2[p*64 + o]; return; } j -= 2048;
  if(j < 32){ ws[OFF_AB2 + j] = ab2[j]; return; } j -= 32;
  if(j < 32){ ws[OFF_W3  + j] = aw3[j]; return; } j -= 32;
  if(j < 1){ ws[OFF_AB3] = ab3[0]; return; } j -= 1;
  if(j < 26624){ // mlp_w1 sliced: [ex8 | i2part22 | poolpart22] per q
    int o = j/208, r = j%208;
    int q = r/52, t = r-52*q;
    int src;
    if(t<8){ int E = (q==0)?0:(8+8*q); src = E + t; }
    else if(t<30){ int d=t-8; int idx = 8*(d>>1)+2*q+(d&1);
                   src = (idx<8) ? (8+idx) : (32+idx); }
    else { int d=t-30; int idx = 8*(d>>1)+2*q+(d&1); src = 120+idx; }
    ws[OFF_M1 + j] = m1[o*208 + src]; return;
  } j -= 26624;
  if(j < 128){ ws[OFF_MB1 + j] = mb1[j]; return; } j -= 128;
  if(j < 8192){ int o=j/64, p=j%64; ws[OFF_M2T + j] = m2[p*128 + o]; return; } j -= 8192;
  if(j < 64){ ws[OFF_MB2 + j] = mb2[j]; return; } j -= 64;
  if(j < 2048){ int o=j/32, p=j%32; ws[OFF_M3T + j] = m3[p*64 + o]; return; } j -= 2048;
  if(j < 32){ ws[OFF_MB3 + j] = mb3[j]; return; } j -= 32;
  if(j < 32){ ws[OFF_M4  + j] = m4[j];  return; } j -= 32;
  if(j < 1){ ws[OFF_MB4] = mb4[0]; return; }
}

// DPP quad reduction: no LDS-pipe traffic (vs ds_swizzle-backed __shfl_xor)
template<int CTL>
__device__ __forceinline__ float qp(float v){
  return __uint_as_float((unsigned)__builtin_amdgcn_update_dpp(
      0, (int)__float_as_uint(v), CTL, 0xF, 0xF, true));
}
__device__ __forceinline__ float bsum4(float v){
  v += qp<0xB1>(v);   // quad_perm [1,0,3,2]  (xor 1)
  v += qp<0x4E>(v);   // quad_perm [2,3,0,1]  (xor 2)
  return v;
}
__device__ __forceinline__ unsigned short f2bf(float f){
  unsigned int u = __float_as_uint(f);
  return (unsigned short)((u + 0x7fffu + ((u>>16)&1u)) >> 16);
}
__device__ __forceinline__ float bf2f(unsigned short s){
  return __uint_as_float(((unsigned int)s) << 16);
}

// async global->LDS staging (dest wave-uniform base + lane*size; all staging
// dests are lane-linear within each wave)
__device__ __forceinline__ void ldst16(void* l, const void* g){
  __builtin_amdgcn_global_load_lds(
      (const __attribute__((address_space(1))) unsigned int*)(uintptr_t)g,
      (__attribute__((address_space(3))) unsigned int*)(uintptr_t)l, 16, 0, 0);
}
__device__ __forceinline__ void ldst4(void* l, const void* g){
  __builtin_amdgcn_global_load_lds(
      (const __attribute__((address_space(1))) unsigned int*)(uintptr_t)g,
      (__attribute__((address_space(3))) unsigned int*)(uintptr_t)l, 4, 0, 0);
}

__device__ __forceinline__ void gather_slice(const float2* __restrict__ itemp,
                                             const float2* __restrict__ kindp,
                                             int item_idx, const int* __restrict__ kidx,
                                             int q, v2f* f){
  float2 v = itemp[item_idx*4 + q];
  f[0] = mk2(v.x, v.y);
  #pragma unroll
  for(int r=0;r<KIND_LEN;r++){
    int ki = kidx[r];
    float2 w = kindp[ki*4 + q];
    bool m = (ki!=0);
    f[1+r] = m ? mk2(w.x, w.y) : mk2(0.f, 0.f);
  }
}

#define PKF(acc, a, b, vv) do{ (acc) = __builtin_elementwise_fma(mk2((a),(b)), (vv), (acc)); }while(0)

// one history pass over NS steps; h=0 weights from LDS f4[0,1536),
// W2T from PF, t2 from bf16 tp cache. Weight reads shared across steps.
template<int NS>
__device__ __forceinline__ void hist_pass(int b, int s0, int q, int wid,
    const float2* __restrict__ item_emb, const float2* __restrict__ kind_emb,
    const int* __restrict__ his_id, const int* __restrict__ his_kind,
    const float* ls, const float4* ls4, const unsigned short* tp, v2f* poolv){
  v2f i1v[NS][11];
  #pragma unroll
  for(int t=0;t<NS;t++)
    gather_slice(item_emb, kind_emb, his_id[b*HIS_LEN + s0 + t],
                 his_kind + (b*HIS_LEN + s0 + t)*KIND_LEN, q, i1v[t]);
  v2f h2v[NS][4];
  #pragma unroll
  for(int t=0;t<NS;t++)
    #pragma unroll
    for(int j=0;j<4;j++) h2v[t][j] = mk2(0.f,0.f);

  #pragma unroll 1
  for(int oo=0;oo<64;oo++){
    const float4* wr = ls4 + oo*24 + 6*q;
    float t2b = bf2f(tp[oo*SB + wid]);
    v2f aA[NS], aB[NS];
    #pragma unroll
    for(int t=0;t<NS;t++){ aA[t]=mk2(0.f,0.f); aB[t]=mk2(0.f,0.f); }
    #pragma unroll
    for(int k=0;k<5;k++){
      float4 w = wr[k];
      #pragma unroll
      for(int t=0;t<NS;t++){
        PKF(aA[t], w.x, w.y, i1v[t][2*k]);
        PKF(aB[t], w.z, w.w, i1v[t][2*k+1]);
      }
    }
    { float4 w = wr[5];
      #pragma unroll
      for(int t=0;t<NS;t++) PKF(aA[t], w.x, w.y, i1v[t][10]); }
    float4 wa = ls4[W2TF4 + oo*8 + 2*q];
    float4 wb = ls4[W2TF4 + 1 + oo*8 + 2*q];
    #pragma unroll
    for(int t=0;t<NS;t++){
      float h = bsum4((aA[t].x+aB[t].x)+(aA[t].y+aB[t].y)) + t2b;
      h = fmaxf(h, 0.f);
      v2f hh = mk2(h, h);
      PKF(h2v[t][0], wa.x, wa.y, hh);
      PKF(h2v[t][1], wa.z, wa.w, hh);
      PKF(h2v[t][2], wb.x, wb.y, hh);
      PKF(h2v[t][3], wb.z, wb.w, hh);
    }
  }
  #pragma unroll
  for(int t=0;t<NS;t++){
    float scp = 0.f;
    #pragma unroll
    for(int jj=0;jj<4;jj++){
      float hx = fmaxf(h2v[t][jj].x + ls[PFF+2112+8*q+2*jj],   0.f);
      float hy = fmaxf(h2v[t][jj].y + ls[PFF+2112+8*q+2*jj+1], 0.f);
      scp += ls[PFF+2144+8*q+2*jj]*hx + ls[PFF+2144+8*q+2*jj+1]*hy;
    }
    float sc = bsum4(scp) + ls[PFF+2176];
    v2f scv = mk2(sc, sc);
    #pragma unroll
    for(int d=0;d<11;d++){
      v2f tt = i1v[t][d]*scv;
      poolv[d] = __builtin_elementwise_fma(tt, i1v[t][d], poolv[d]);
    }
  }
}

__device__ __forceinline__ void mlp_stage(int c, int tid, float* ls, float4* ls4,
                                          const float* ws, const float4* ws4){
  int base = 1536 + (c&1)*768;
  int j = tid;   // 544 f4: M1S 416 | M2T 128
  const float4* src = (j<416) ? (ws4 + 3680 + c*416 + j)
                              : (ws4 + 10368 + c*128 + (j-416));
  ldst16(ls4 + base + j, src);
  if(tid < 32) ldst16(ls4 + base + 512 + tid, ws4 + 10368 + c*128 + 96 + tid);
  if(tid < 8)  ldst4(ls + base*4 + 2176 + tid, ws + OFF_MB1 + c*8 + tid);
}

// 512 threads; 128 samples/block; quad (q=lane&3) K-splits every dot.
__global__ void __launch_bounds__(NTH, 4)
din_main(const int* __restrict__ userid, const int* __restrict__ itemid,
         const int* __restrict__ age,    const int* __restrict__ gen,
         const int* __restrict__ occ,    const int* __restrict__ item_kind,
         const int* __restrict__ his_id, const int* __restrict__ his_kind,
         const float2* __restrict__ user_emb, const float2* __restrict__ item_emb,
         const float2* __restrict__ age_emb,  const float2* __restrict__ gen_emb,
         const float2* __restrict__ occ_emb,  const float2* __restrict__ kind_emb,
         const float* __restrict__ ws, float* __restrict__ out){
  const int tid  = threadIdx.x;
  const int q    = tid & 3;
  const int sl   = (tid & 63) >> 2;
  const int wv   = __builtin_amdgcn_readfirstlane(tid >> 6);
  const int wid  = wv*16 + sl;                 // sample-in-block 0..127
  const int b    = blockIdx.x*SB + wid;

  __shared__ __align__(16) float ls[LDSF];
  float4* ls4 = (float4*)ls;
  const float* wsc = ws;
  const float4* ws4 = (const float4*)ws;
  unsigned short* tp = (unsigned short*)(ls + PFF + 2306);

  // ---- initial async staging: PF (2306 f) + BOTH act-w1 halves (3072 f4) ----
  #pragma unroll
  for(int k=0;k<4;k++){ int j = k*NTH + tid; ldst4(ls + PFF + j, wsc + 12288 + j); }
  { int j = 4*NTH + tid;
    if(j < 2306){
      const float* src = (j<2177) ? (wsc + 12288 + j)
                       : (j<2241) ? (wsc + 49664 + (j-2177))
                                  : (wsc + 51776 + (j-2241));
      ldst4(ls + PFF + j, src);
    } }
  #pragma unroll
  for(int k=0;k<6;k++){
    int j = k*NTH + tid;                 // 0..3071
    int half = (j >= 1536) ? 1 : 0;
    int jj = j - half*1536;
    int o = jj/24, d = jj - o*24;
    ldst16(ls4 + j, ws4 + o*48 + half*24 + d);
  }

  // ---- i2 slice (overlaps staging latency) ----
  v2f i2v[11];
  gather_slice(item_emb, kind_emb, itemid[b], item_kind + b*KIND_LEN, q, i2v);

  __syncthreads();   // all staging drained

  // ---- phase A: t2+ab1 -> bf16 tp (h=1 weights, LDS f4[1536,3072)) ----
  // tp entries are written and later read by the SAME quad.
  #pragma unroll 2
  for(int oo=0;oo<64;oo++){
    const float4* wr = ls4 + 1536 + oo*24 + 6*q;
    v2f aA = mk2(0.f,0.f), aB = mk2(0.f,0.f);
    #pragma unroll
    for(int k=0;k<5;k++){
      float4 w = wr[k];
      PKF(aA, w.x, w.y, i2v[2*k]);
      PKF(aB, w.z, w.w, i2v[2*k+1]);
    }
    { float4 w = wr[5]; PKF(aA, w.x, w.y, i2v[10]); }
    float s = bsum4((aA.x+aB.x)+(aA.y+aB.y));
    if(q==0) tp[oo*SB + wid] = f2bf(s + ls[PFF + oo]);
  }

  __syncthreads();   // all waves done reading h=1 region

  // prefetch MLP chunks 0,1 into the (now free) h=1 region; history hides it
  mlp_stage(0, tid, ls, ls4, wsc, ws4);
  mlp_stage(1, tid, ls, ls4, wsc, ws4);

  // ---- history: 3 passes (2+2+1 steps), no barriers ----
  v2f poolv[11];
  #pragma unroll
  for(int d=0;d<11;d++) poolv[d]=mk2(0.f,0.f);
  hist_pass<2>(b, 0, q, wid, item_emb, kind_emb, his_id, his_kind, ls, ls4, tp, poolv);
  hist_pass<2>(b, 2, q, wid, item_emb, kind_emb, his_id, his_kind, ls, ls4, tp, poolv);
  hist_pass<1>(b, 4, q, wid, item_emb, kind_emb, his_id, his_kind, ls, ls4, tp, poolv);

  // ---- MLP prologue: re-gather i2 (frees regs during history), extras, h2m ----
  gather_slice(item_emb, kind_emb, itemid[b], item_kind + b*KIND_LEN, q, i2v);
  v2f exv[4];
  {
    const float2* ep = (q==0)? user_emb : (q==1)? age_emb : (q==2)? gen_emb : occ_emb;
    int ei = (q==0)? userid[b] : (q==1)? age[b] : (q==2)? gen[b] : occ[b];
    #pragma unroll
    for(int k=0;k<4;k++){ float2 v = ep[ei*4+k]; exv[k]=mk2(v.x,v.y); }
  }
  v2f h2m[8];
  #pragma unroll
  for(int j=0;j<8;j++) h2m[j] = mk2(ls[PFF+2177+16*q+2*j], ls[PFF+2177+16*q+2*j+1]);

  __syncthreads();   // drains chunk 0,1 loads; aligns waves

  // ---- MLP layers 1+2: 16 chunks; compute c, barrier, stage c+2 ----
  #pragma unroll 1
  for(int c=0;c<16;c++){
    int base = 1536 + (c&1)*768;
    int fb   = base*4;
    #pragma unroll 1
    for(int i=0;i<8;i++){
      const float4* wr = ls4 + base + i*52 + 13*q;
      v2f aA = mk2(0.f,0.f), aB = mk2(0.f,0.f);
      { float4 w = wr[0]; PKF(aA, w.x, w.y, exv[0]); PKF(aB, w.z, w.w, exv[1]); }
      { float4 w = wr[1]; PKF(aA, w.x, w.y, exv[2]); PKF(aB, w.z, w.w, exv[3]); }
      #pragma unroll
      for(int k=0;k<5;k++){
        float4 w = wr[2+k];
        PKF(aA, w.x, w.y, i2v[2*k]);
        PKF(aB, w.z, w.w, i2v[2*k+1]);
      }
      { float4 w = wr[7]; PKF(aA, w.x, w.y, i2v[10]); PKF(aB, w.z, w.w, poolv[0]); }
      #pragma unroll
      for(int k=0;k<5;k++){
        float4 w = wr[8+k];
        PKF(aA, w.x, w.y, poolv[2*k+1]);
        PKF(aB, w.z, w.w, poolv[2*k+2]);
      }
      float h = fmaxf(bsum4((aA.x+aB.x)+(aA.y+aB.y)) + ls[fb + 2176 + i], 0.f);
      v2f hh = mk2(h, h);
      const float4* w2 = ls4 + base + 416 + i*16 + 4*q;
      #pragma unroll
      for(int k=0;k<4;k++){
        float4 w = w2[k];
        PKF(h2m[2*k],   w.x, w.y, hh);
        PKF(h2m[2*k+1], w.z, w.w, hh);
      }
    }
    __syncthreads();          // all waves done with buf[c&1]; drains last stage
    if(c < 14){
      mlp_stage(c+2, tid, ls, ls4, wsc, ws4);   // into buf[c&1], 2 ahead
    } else if(c == 14){
      // tail: stage M3T with per-q skew (row 16q+i at f4 1536+q*130+i*8)
      int j = tid;
      ldst16(ls4 + 1536 + (j>>7)*130 + (j&127), ws4 + 12432 + j);
    }
  }
  // c==15's loop-end barrier drained the M3T loads

  // ---- tail: layers 3+4, grouped 8 outputs at a time ----
  float hv[16];
  #pragma unroll
  for(int j=0;j<16;j++) hv[j] = fmaxf((j&1) ? h2m[j>>1].y : h2m[j>>1].x, 0.f);

  float x = ls[PFF+2305];
  #pragma unroll
  for(int g=0;g<4;g++){
    float a[8];
    #pragma unroll
    for(int j=0;j<8;j++) a[j]=0.f;
    #pragma unroll
    for(int i=0;i<16;i++){
      float4 wA = ls4[1536 + q*130 + i*8 + 2*g];
      float4 wB = ls4[1536 + q*130 + i*8 + 2*g + 1];
      a[0]+=wA.x*hv[i]; a[1]+=wA.y*hv[i]; a[2]+=wA.z*hv[i]; a[3]+=wA.w*hv[i];
      a[4]+=wB.x*hv[i]; a[5]+=wB.y*hv[i]; a[6]+=wB.z*hv[i]; a[7]+=wB.w*hv[i];
    }
    #pragma unroll
    for(int j=0;j<8;j++) a[j] = bsum4(a[j]);
    #pragma unroll
    for(int j=0;j<8;j++)
      x += ls[PFF+2273+8*g+j] * fmaxf(a[j] + ls[PFF+2241+8*g+j], 0.f);
  }

  if(q==0) out[b] = 1.0f/(1.0f + __expf(-x));
}

extern "C" void kernel_launch(void* const* d_in, const int* in_sizes, int n_in,
                              void* d_out, int out_size, void* d_ws, size_t ws_size,
                              hipStream_t stream){
  const int* userid    = (const int*)d_in[0];
  const int* itemid    = (const int*)d_in[1];
  const int* age       = (const int*)d_in[2];
  const int* gen       = (const int*)d_in[3];
  const int* occ       = (const int*)d_in[4];
  const int* item_kind = (const int*)d_in[5];
  const int* his_id    = (const int*)d_in[6];
  const int* his_kind  = (const int*)d_in[7];
  const float2* user_emb = (const float2*)d_in[8];
  const float2* item_emb = (const float2*)d_in[9];
  const float2* age_emb  = (const float2*)d_in[10];
  const float2* gen_emb  = (const float2*)d_in[11];
  const float2* occ_emb  = (const float2*)d_in[12];
  const float2* kind_emb = (const float2*)d_in[13];
  float* ws = (float*)d_ws;

  din_prep<<<(PREP_N+255)/256, 256, 0, stream>>>(
      (fp)d_in[14], (fp)d_in[15], (fp)d_in[16], (fp)d_in[17], (fp)d_in[18], (fp)d_in[19],
      (fp)d_in[20], (fp)d_in[21], (fp)d_in[22], (fp)d_in[23], (fp)d_in[24], (fp)d_in[25],
      (fp)d_in[26], (fp)d_in[27], ws);

  din_main<<<BATCH/SB, NTH, 0, stream>>>(
      userid, itemid, age, gen, occ, item_kind, his_id, his_kind,
      user_emb, item_emb, age_emb, gen_emb, occ_emb, kind_emb,
      ws, (float*)d_out);
}

// Round 7
// 290.529 us; speedup vs baseline: 2.5771x; 1.1970x over previous
//
#include <hip/hip_runtime.h>
#include <cstdint>
#include <math.h>

#define BATCH    65536
#define HIS_LEN  5
#define KIND_LEN 10
#define SB       128   // samples per block
#define NTH      512   // threads per block (8 waves); 4 threads per sample

typedef float    v2f __attribute__((ext_vector_type(2)));
typedef _Float16 v2h __attribute__((ext_vector_type(2)));
__device__ __forceinline__ v2f mk2(float a, float b){ v2f r; r.x=a; r.y=b; return r; }
#define C2H(u) __builtin_bit_cast(v2h,(unsigned)(u))

#if __has_builtin(__builtin_amdgcn_fdot2)
__device__ __forceinline__ float FD2(v2h a, v2h b, float c){
  return __builtin_amdgcn_fdot2(a, b, c, false);   // v_dot2_f32_f16
}
#else
__device__ __forceinline__ float FD2(v2h a, v2h b, float c){
  return c + (float)a.x*(float)b.x + (float)a.y*(float)b.y;
}
#endif

__device__ __forceinline__ unsigned short f2h(float f){
  return __builtin_bit_cast(unsigned short, (_Float16)f);
}
__device__ __forceinline__ float h2f(unsigned short s){
  return (float)__builtin_bit_cast(_Float16, s);
}
__device__ __forceinline__ unsigned pack2h(float a, float b){
  return (unsigned)f2h(a) | ((unsigned)f2h(b) << 16);
}
__device__ __forceinline__ v2h pkh(float a, float b){
  return __builtin_bit_cast(v2h, __builtin_amdgcn_cvt_pkrtz(a, b));
}

// ---- ws layout (dword offsets) ----
#define OFF_WC1H 0      // 6144  f16x2: [h][64 o][4 q][12 dw] (22 data + 2 pad)
#define OFF_AB1  6144   // 64    f32
#define OFF_W2T  6208   // 2048  f32 [o*32+p]
#define OFF_AB2  8256   // 32
#define OFF_W3   8288   // 32
#define OFF_AB3  8320   // 1  (+3 pad)
#define OFF_M1H  8324   // 14336 f16x2: [128 o][4 q][28 dw] (52 data + 4 pad)
#define OFF_MB1  22660  // 128
#define OFF_M2T  22788  // 8192  f32 [o*64+p]
#define OFF_MB2  30980  // 64
#define OFF_M3T  31044  // 2048  f32 [o*32+p]
#define OFF_MB3  33092  // 32
#define OFF_M4   33124  // 32
#define OFF_MB4  33156  // 1
#define PREP_N   33157
// f4 indices into ws
#define M1H4  2081      // 8324/4
#define M2T4  5697      // 22788/4
#define M3T4  7761      // 31044/4

// ---- LDS float layout ----
//  f4 [0,768):    W1C16 h=0 (history weights); reused for skewed M3T at tail
//  f4 [768,1536): W1C16 h=1 (phase A); reused as two 384-f4 MLP chunk bufs
//  [6144,8450):   PF = AB1(64)|W2T(2048)|AB2(32)|W3(32)|AB3(1)|MB2(64)|MB3(32)|M4(32)|MB4(1)
//  [8450,8466):   MLP bias double-slot (8 per chunk parity)
//  [8466,12562):  tp: 8192 f16 = 64 outputs x 128 samples (t2 + ab1)
#define PFF   6144
#define W2TF4 1552      // 6208/4
#define MBB   8450
#define TPF   8466
#define LDSF  12562

typedef const float* fp;

__device__ __forceinline__ float m1s_val(fp m1, int o, int q, int t){
  if(t >= 52) return 0.f;
  int src;
  if(t<8){ int E = (q==0)?0:(8+8*q); src = E + t; }
  else if(t<30){ int d=t-8; int idx = 8*(d>>1)+2*q+(d&1);
                 src = (idx<8) ? (8+idx) : (32+idx); }
  else { int d=t-30; int idx = 8*(d>>1)+2*q+(d&1); src = 120+idx; }
  return m1[o*208 + src];
}
__device__ __forceinline__ float w1c_val(fp aw1, int o, int q, int h, int d){
  if(d >= 22) return 0.f;
  int idx = 8*(d>>1) + 2*q + (d&1);
  return h ? (aw1[o*264+176+idx] - aw1[o*264+88+idx])
           : (aw1[o*264+idx]     + aw1[o*264+88+idx]);
}

// lane q owns feature elements idx = 8r + 2q + e (r<11, e<2) of each 88-vec
__global__ void din_prep(fp aw1, fp ab1, fp aw2, fp ab2, fp aw3, fp ab3,
                         fp m1,  fp mb1, fp m2,  fp mb2, fp m3,  fp mb3,
                         fp m4,  fp mb4, float* __restrict__ ws){
  int j = blockIdx.x*blockDim.x + threadIdx.x;
  unsigned* wsu = (unsigned*)ws;
  if(j < 6144){ // W1C16 packed f16 pairs: [h][64 o][4 q][12 dw]
    int h = j/3072, r = j%3072;
    int slot = r/12, dw = r - slot*12;
    int o = slot>>2, q = slot&3;
    wsu[OFF_WC1H + j] = pack2h(w1c_val(aw1,o,q,h,2*dw), w1c_val(aw1,o,q,h,2*dw+1));
    return;
  } j -= 6144;
  if(j < 64){ ws[OFF_AB1 + j] = ab1[j]; return; } j -= 64;
  if(j < 2048){ int o=j/32, p=j%32; ws[OFF_W2T + j] = aw2[p*64 + o]; return; } j -= 2048;
  if(j < 32){ ws[OFF_AB2 + j] = ab2[j]; return; } j -= 32;
  if(j < 32){ ws[OFF_W3  + j] = aw3[j]; return; } j -= 32;
  if(j < 1){ ws[OFF_AB3] = ab3[0]; return; } j -= 1;
  if(j < 3){ ws[OFF_AB3+1+j] = 0.f; return; } j -= 3;   // pad
  if(j < 14336){ // M1SH packed f16 pairs: [128 o][4 q][28 dw]
    int slot = j/28, dw = j - slot*28;
    int o = slot>>2, q = slot&3;
    wsu[OFF_M1H + j] = pack2h(m1s_val(m1,o,q,2*dw), m1s_val(m1,o,q,2*dw+1));
    return;
  } j -= 14336;
  if(j < 128){ ws[OFF_MB1 + j] = mb1[j]; return; } j -= 128;
  if(j < 8192){ int o=j/64, p=j%64; ws[OFF_M2T + j] = m2[p*128 + o]; return; } j -= 8192;
  if(j < 64){ ws[OFF_MB2 + j] = mb2[j]; return; } j -= 64;
  if(j < 2048){ int o=j/32, p=j%32; ws[OFF_M3T + j] = m3[p*64 + o]; return; } j -= 2048;
  if(j < 32){ ws[OFF_MB3 + j] = mb3[j]; return; } j -= 32;
  if(j < 32){ ws[OFF_M4  + j] = m4[j];  return; } j -= 32;
  if(j < 1){ ws[OFF_MB4] = mb4[0]; return; }
}

// DPP quad reduction: no LDS-pipe traffic
template<int CTL>
__device__ __forceinline__ float qp(float v){
  return __uint_as_float((unsigned)__builtin_amdgcn_update_dpp(
      0, (int)__float_as_uint(v), CTL, 0xF, 0xF, true));
}
__device__ __forceinline__ float bsum4(float v){
  v += qp<0xB1>(v);   // quad_perm [1,0,3,2]  (xor 1)
  v += qp<0x4E>(v);   // quad_perm [2,3,0,1]  (xor 2)
  return v;
}

// async global->LDS staging (dest wave-uniform base + lane*size; all staging
// dests are lane-linear within each wave)
__device__ __forceinline__ void ldst16(void* l, const void* g){
  __builtin_amdgcn_global_load_lds(
      (const __attribute__((address_space(1))) unsigned int*)(uintptr_t)g,
      (__attribute__((address_space(3))) unsigned int*)(uintptr_t)l, 16, 0, 0);
}
__device__ __forceinline__ void ldst4(void* l, const void* g){
  __builtin_amdgcn_global_load_lds(
      (const __attribute__((address_space(1))) unsigned int*)(uintptr_t)g,
      (__attribute__((address_space(3))) unsigned int*)(uintptr_t)l, 4, 0, 0);
}

// gather one 88-feature quad-slice as 11 packed f16 pairs
__device__ __forceinline__ void gather_h(const float2* __restrict__ itemp,
                                         const float2* __restrict__ kindp,
                                         int item_idx, const int* __restrict__ kidx,
                                         int q, v2h* f){
  float2 v = itemp[item_idx*4 + q];
  f[0] = pkh(v.x, v.y);
  #pragma unroll
  for(int r=0;r<KIND_LEN;r++){
    int ki = kidx[r];
    float2 w = kindp[ki*4 + q];
    float mx = ki ? w.x : 0.f, my = ki ? w.y : 0.f;
    f[1+r] = pkh(mx, my);
  }
}

#define PKF(acc, a, b, vv) do{ (acc) = __builtin_elementwise_fma(mk2((a),(b)), (vv), (acc)); }while(0)

// one history pass over NS steps; f16 weights from LDS f4[0,768),
// W2T f32 from PF, t2 from f16 tp cache. Weight reads shared across steps.
template<int NS>
__device__ __forceinline__ void hist_pass(int b, int s0, int q, int wid,
    const float2* __restrict__ item_emb, const float2* __restrict__ kind_emb,
    const int* __restrict__ his_id, const int* __restrict__ his_kind,
    const float* ls, const float4* ls4, const unsigned short* tp, v2f* poolv){
  v2h i1h[NS][11];
  #pragma unroll
  for(int t=0;t<NS;t++)
    gather_h(item_emb, kind_emb, his_id[b*HIS_LEN + s0 + t],
             his_kind + (b*HIS_LEN + s0 + t)*KIND_LEN, q, i1h[t]);
  v2f h2v[NS][4];
  #pragma unroll
  for(int t=0;t<NS;t++)
    #pragma unroll
    for(int j=0;j<4;j++) h2v[t][j] = mk2(0.f,0.f);

  #pragma unroll 1
  for(int oo=0;oo<64;oo++){
    const uint4* wr = (const uint4*)(ls4 + (oo*4+q)*3);
    uint4 r0 = wr[0], r1 = wr[1], r2 = wr[2];
    unsigned dwv[12] = {r0.x,r0.y,r0.z,r0.w, r1.x,r1.y,r1.z,r1.w, r2.x,r2.y,r2.z,r2.w};
    float t2b = h2f(tp[oo*SB + wid]);
    float aA[NS], aB[NS];
    #pragma unroll
    for(int t=0;t<NS;t++){ aA[t]=0.f; aB[t]=0.f; }
    #pragma unroll
    for(int u=0;u<11;u++){
      #pragma unroll
      for(int t=0;t<NS;t++){
        if(u&1) aB[t] = FD2(C2H(dwv[u]), i1h[t][u], aB[t]);
        else    aA[t] = FD2(C2H(dwv[u]), i1h[t][u], aA[t]);
      }
    }
    float4 wa = ls4[W2TF4 + oo*8 + 2*q];
    float4 wb = ls4[W2TF4 + 1 + oo*8 + 2*q];
    #pragma unroll
    for(int t=0;t<NS;t++){
      float h = bsum4(aA[t]+aB[t]) + t2b;
      h = fmaxf(h, 0.f);
      v2f hh = mk2(h, h);
      PKF(h2v[t][0], wa.x, wa.y, hh);
      PKF(h2v[t][1], wa.z, wa.w, hh);
      PKF(h2v[t][2], wb.x, wb.y, hh);
      PKF(h2v[t][3], wb.z, wb.w, hh);
    }
  }
  #pragma unroll
  for(int t=0;t<NS;t++){
    float scp = 0.f;
    #pragma unroll
    for(int jj=0;jj<4;jj++){
      float hx = fmaxf(h2v[t][jj].x + ls[PFF+2112+8*q+2*jj],   0.f);
      float hy = fmaxf(h2v[t][jj].y + ls[PFF+2112+8*q+2*jj+1], 0.f);
      scp += ls[PFF+2144+8*q+2*jj]*hx + ls[PFF+2144+8*q+2*jj+1]*hy;
    }
    float sc = bsum4(scp) + ls[PFF+2176];
    #pragma unroll
    for(int j=0;j<11;j++){
      float sx = (float)i1h[t][j].x, sy = (float)i1h[t][j].y;
      poolv[j] = __builtin_elementwise_fma(mk2(sx*sc, sy*sc), mk2(sx, sy), poolv[j]);
    }
  }
}

__device__ __forceinline__ void mlp_stage(int c, int tid, float* ls, float4* ls4,
                                          const float* ws, const float4* ws4){
  int base = 768 + (c&1)*384;
  if(tid < 352){   // 224 f4 M1SH + 128 f4 M2T
    const float4* src = (tid < 224) ? (ws4 + M1H4 + c*224 + tid)
                                    : (ws4 + M2T4 + c*128 + (tid-224));
    ldst16(ls4 + base + tid, src);
  }
  if(tid < 8) ldst4(ls + MBB + (c&1)*8 + tid, ws + OFF_MB1 + c*8 + tid);
}

// 512 threads; 128 samples/block; quad (q=lane&3) K-splits every dot.
__global__ void __launch_bounds__(NTH, 4)
din_main(const int* __restrict__ userid, const int* __restrict__ itemid,
         const int* __restrict__ age,    const int* __restrict__ gen,
         const int* __restrict__ occ,    const int* __restrict__ item_kind,
         const int* __restrict__ his_id, const int* __restrict__ his_kind,
         const float2* __restrict__ user_emb, const float2* __restrict__ item_emb,
         const float2* __restrict__ age_emb,  const float2* __restrict__ gen_emb,
         const float2* __restrict__ occ_emb,  const float2* __restrict__ kind_emb,
         const float* __restrict__ ws, float* __restrict__ out){
  const int tid  = threadIdx.x;
  const int q    = tid & 3;
  const int sl   = (tid & 63) >> 2;
  const int wv   = __builtin_amdgcn_readfirstlane(tid >> 6);
  const int wid  = wv*16 + sl;                 // sample-in-block 0..127
  const int b    = blockIdx.x*SB + wid;

  __shared__ __align__(16) float ls[LDSF];
  float4* ls4 = (float4*)ls;
  const float* wsc = ws;
  const float4* ws4 = (const float4*)ws;
  unsigned short* tp = (unsigned short*)(ls + TPF);

  // ---- initial async staging: PF (2306 f) + W1C16 both halves (1536 f4) ----
  #pragma unroll
  for(int k=0;k<4;k++){ int j = k*NTH + tid; ldst4(ls + PFF + j, wsc + OFF_AB1 + j); }
  if(tid < 129) ldst4(ls + PFF + 2048 + tid, wsc + OFF_AB1 + 2048 + tid);
  if(tid < 64)  ldst4(ls + PFF + 2177 + tid, wsc + OFF_MB2 + tid);
  if(tid < 65)  ldst4(ls + PFF + 2241 + tid, wsc + OFF_MB3 + tid);
  #pragma unroll
  for(int k=0;k<3;k++){ int j = k*NTH + tid; ldst16(ls4 + j, ws4 + j); }

  // ---- i2 slice as packed f16 (overlaps staging latency); lives all kernel ----
  v2h i2h[11];
  gather_h(item_emb, kind_emb, itemid[b], item_kind + b*KIND_LEN, q, i2h);

  __syncthreads();   // all staging drained

  // ---- phase A: t2+ab1 -> f16 tp (h=1 weights, f4 [768,1536)) ----
  // tp entries are written and later read by the SAME quad.
  #pragma unroll 2
  for(int oo=0;oo<64;oo++){
    const uint4* wr = (const uint4*)(ls4 + 768 + (oo*4+q)*3);
    uint4 r0 = wr[0], r1 = wr[1], r2 = wr[2];
    unsigned dwv[12] = {r0.x,r0.y,r0.z,r0.w, r1.x,r1.y,r1.z,r1.w, r2.x,r2.y,r2.z,r2.w};
    float aA = 0.f, aB = 0.f;
    #pragma unroll
    for(int u=0;u<11;u++){
      if(u&1) aB = FD2(C2H(dwv[u]), i2h[u], aB);
      else    aA = FD2(C2H(dwv[u]), i2h[u], aA);
    }
    float s = bsum4(aA+aB);
    if(q==0) tp[oo*SB + wid] = f2h(s + ls[PFF + oo]);
  }

  __syncthreads();   // all waves done reading h=1 region

  // prefetch MLP chunks 0,1 into the (now free) h=1 region; history hides it
  mlp_stage(0, tid, ls, ls4, wsc, ws4);
  mlp_stage(1, tid, ls, ls4, wsc, ws4);

  // ---- history: 3 passes (2+2+1 steps), no barriers ----
  v2f poolv[11];
  #pragma unroll
  for(int d=0;d<11;d++) poolv[d]=mk2(0.f,0.f);
  hist_pass<2>(b, 0, q, wid, item_emb, kind_emb, his_id, his_kind, ls, ls4, tp, poolv);
  hist_pass<2>(b, 2, q, wid, item_emb, kind_emb, his_id, his_kind, ls, ls4, tp, poolv);
  hist_pass<1>(b, 4, q, wid, item_emb, kind_emb, his_id, his_kind, ls, ls4, tp, poolv);

  // ---- MLP prologue: pack features, extras, h2m init ----
  v2h poolh[11];
  #pragma unroll
  for(int j=0;j<11;j++) poolh[j] = pkh(poolv[j].x, poolv[j].y);
  v2h fe[26];
  {
    const float2* ep = (q==0)? user_emb : (q==1)? age_emb : (q==2)? gen_emb : occ_emb;
    int ei = (q==0)? userid[b] : (q==1)? age[b] : (q==2)? gen[b] : occ[b];
    #pragma unroll
    for(int k=0;k<4;k++){ float2 v = ep[ei*4+k]; fe[k] = pkh(v.x, v.y); }
  }
  #pragma unroll
  for(int j=0;j<11;j++) fe[4+j]  = i2h[j];
  #pragma unroll
  for(int j=0;j<11;j++) fe[15+j] = poolh[j];
  v2f h2m[8];
  #pragma unroll
  for(int j=0;j<8;j++) h2m[j] = mk2(ls[PFF+2177+16*q+2*j], ls[PFF+2177+16*q+2*j+1]);

  __syncthreads();   // drains chunk 0,1 loads; aligns waves

  // ---- MLP layers 1+2: 16 chunks; compute c, barrier, stage c+2 ----
  #pragma unroll 1
  for(int c=0;c<16;c++){
    int base = 768 + (c&1)*384;
    #pragma unroll 1
    for(int i=0;i<8;i++){
      const uint4* wr = (const uint4*)(ls4 + base + (i*4+q)*7);
      unsigned dwv[28];
      #pragma unroll
      for(int k=0;k<7;k++){
        uint4 t = wr[k];
        dwv[4*k]=t.x; dwv[4*k+1]=t.y; dwv[4*k+2]=t.z; dwv[4*k+3]=t.w;
      }
      float aA = 0.f, aB = 0.f;
      #pragma unroll
      for(int u=0;u<26;u++){
        if(u&1) aB = FD2(C2H(dwv[u]), fe[u], aB);
        else    aA = FD2(C2H(dwv[u]), fe[u], aA);
      }
      float h = fmaxf(bsum4(aA+aB) + ls[MBB + (c&1)*8 + i], 0.f);
      v2f hh = mk2(h, h);
      const float4* w2 = ls4 + base + 224 + i*16 + 4*q;
      #pragma unroll
      for(int k=0;k<4;k++){
        float4 w = w2[k];
        PKF(h2m[2*k],   w.x, w.y, hh);
        PKF(h2m[2*k+1], w.z, w.w, hh);
      }
    }
    __syncthreads();          // all waves done with buf[c&1]; drains last stage
    if(c < 14){
      mlp_stage(c+2, tid, ls, ls4, wsc, ws4);   // into buf[c&1], 2 ahead
    } else if(c == 14){
      // tail: stage M3T with per-q skew (row 16q+i at f4 q*130+i*8) into h0 region
      int j = tid;
      ldst16(ls4 + (j>>7)*130 + (j&127), ws4 + M3T4 + j);
    }
  }
  // c==15's loop-end barrier drained the M3T loads

  // ---- tail: layers 3+4, grouped 8 outputs at a time ----
  float hv[16];
  #pragma unroll
  for(int j=0;j<16;j++) hv[j] = fmaxf((j&1) ? h2m[j>>1].y : h2m[j>>1].x, 0.f);

  float x = ls[PFF+2305];
  #pragma unroll
  for(int g=0;g<4;g++){
    float a[8];
    #pragma unroll
    for(int j=0;j<8;j++) a[j]=0.f;
    #pragma unroll
    for(int i=0;i<16;i++){
      float4 wA = ls4[q*130 + i*8 + 2*g];
      float4 wB = ls4[q*130 + i*8 + 2*g + 1];
      a[0]+=wA.x*hv[i]; a[1]+=wA.y*hv[i]; a[2]+=wA.z*hv[i]; a[3]+=wA.w*hv[i];
      a[4]+=wB.x*hv[i]; a[5]+=wB.y*hv[i]; a[6]+=wB.z*hv[i]; a[7]+=wB.w*hv[i];
    }
    #pragma unroll
    for(int j=0;j<8;j++) a[j] = bsum4(a[j]);
    #pragma unroll
    for(int j=0;j<8;j++)
      x += ls[PFF+2273+8*g+j] * fmaxf(a[j] + ls[PFF+2241+8*g+j], 0.f);
  }

  if(q==0) out[b] = 1.0f/(1.0f + __expf(-x));
}

extern "C" void kernel_launch(void* const* d_in, const int* in_sizes, int n_in,
                              void* d_out, int out_size, void* d_ws, size_t ws_size,
                              hipStream_t stream){
  const int* userid    = (const int*)d_in[0];
  const int* itemid    = (const int*)d_in[1];
  const int* age       = (const int*)d_in[2];
  const int* gen       = (const int*)d_in[3];
  const int* occ       = (const int*)d_in[4];
  const int* item_kind = (const int*)d_in[5];
  const int* his_id    = (const int*)d_in[6];
  const int* his_kind  = (const int*)d_in[7];
  const float2* user_emb = (const float2*)d_in[8];
  const float2* item_emb = (const float2*)d_in[9];
  const float2* age_emb  = (const float2*)d_in[10];
  const float2* gen_emb  = (const float2*)d_in[11];
  const float2* occ_emb  = (const float2*)d_in[12];
  const float2* kind_emb = (const float2*)d_in[13];
  float* ws = (float*)d_ws;

  din_prep<<<(PREP_N+255)/256, 256, 0, stream>>>(
      (fp)d_in[14], (fp)d_in[15], (fp)d_in[16], (fp)d_in[17], (fp)d_in[18], (fp)d_in[19],
      (fp)d_in[20], (fp)d_in[21], (fp)d_in[22], (fp)d_in[23], (fp)d_in[24], (fp)d_in[25],
      (fp)d_in[26], (fp)d_in[27], ws);

  din_main<<<BATCH/SB, NTH, 0, stream>>>(
      userid, itemid, age, gen, occ, item_kind, his_id, his_kind,
      user_emb, item_emb, age_emb, gen_emb, occ_emb, kind_emb,
      ws, (float*)d_out);
}

// Round 8
// 285.382 us; speedup vs baseline: 2.6235x; 1.0180x over previous
//
#include <hip/hip_runtime.h>
#include <cstdint>
#include <math.h>

#define BATCH    65536
#define HIS_LEN  5
#define KIND_LEN 10
#define SB       128   // samples per block
#define NTH      512   // threads per block (8 waves); 4 threads per sample

typedef float    v2f __attribute__((ext_vector_type(2)));
typedef _Float16 v2h __attribute__((ext_vector_type(2)));
__device__ __forceinline__ v2f mk2(float a, float b){ v2f r; r.x=a; r.y=b; return r; }
#define C2H(u) __builtin_bit_cast(v2h,(unsigned)(u))

#if __has_builtin(__builtin_amdgcn_fdot2)
__device__ __forceinline__ float FD2(v2h a, v2h b, float c){
  return __builtin_amdgcn_fdot2(a, b, c, false);   // v_dot2_f32_f16
}
#else
__device__ __forceinline__ float FD2(v2h a, v2h b, float c){
  return c + (float)a.x*(float)b.x + (float)a.y*(float)b.y;
}
#endif

__device__ __forceinline__ unsigned short f2h(float f){
  return __builtin_bit_cast(unsigned short, (_Float16)f);
}
__device__ __forceinline__ unsigned pack2h(float a, float b){
  return (unsigned)f2h(a) | ((unsigned)f2h(b) << 16);
}
__device__ __forceinline__ v2h pkh(float a, float b){
  return __builtin_bit_cast(v2h, __builtin_amdgcn_cvt_pkrtz(a, b));
}

// ---- ws layout (dword offsets) ----
#define OFF_WC1H 0      // 6144  f16x2: [h][64 o][4 q][12 dw] (22 data + 2 pad)
#define OFF_AB1  6144   // 64    f32
#define OFF_W2H  7208   // placeholder (see below) -- real values next lines
#undef  OFF_W2H
#define OFF_W2H  6208   // 1024  f16x2 pairs: [32 pp][4 q][8 dw]; dw j -> out 8q+j, pair (2pp,2pp+1)
#define OFF_AB2  7232   // 32
#define OFF_W3   7264   // 32
#define OFF_AB3  7296   // 1
#define OFF_MB2  7297   // 64
#define OFF_MB3  7361   // 32
#define OFF_M4   7393   // 32
#define OFF_MB4  7425   // 1   -> PF block ws[6144,7426) = 1282 floats
#define OFF_M3H  7428   // 1024 f16x2 pairs: [4 q][8 ip][32 dw]; dw=out, pair in=(16q+2ip,+1)
#define OFF_M1H  8452   // 14336 f16x2: [128 o][4 q][28 dw] (52 data + 4 pad)
#define OFF_MB1  22788  // 128
#define OFF_M2H  22916  // 4096 f16x2 pairs: [64 gp][4 q][16 dw]; dw k -> out 16q+k, pair in=(2gp,2gp+1)
#define PREP_N   27012
// f4 indices into ws
#define M1H4  2113      // 8452/4
#define M2H4  5729      // 22916/4
#define M3H4  1857      // 7428/4

// ---- LDS float layout ----
//  f4 [0,768):    W1C16 h=0 (history); tail reuses for skewed M3H (f4 [0,262))
//  f4 [768,1536): W1C16 h=1 (phase A); then two 288-f4 MLP chunk bufs [768,1344)
//  [6144,7426):   PF = AB1(64)|W2H(1024dw)|AB2(32)|W3(32)|AB3(1)|MB2(64)|MB3(32)|M4(32)|MB4(1)
//  [7426,7442):   MLP bias double-slot (8 per chunk parity)
//  [7442,11538):  tp: 4096 dwords = 32 oo-pairs x 128 samples (f16 pair: t2+ab1)
#define PFF   6144
#define W2HF4 1552      // (PFF+64)/4
#define MBB   7426
#define TPF   7442
#define LDSF  11538

typedef const float* fp;

__device__ __forceinline__ float m1s_val(fp m1, int o, int q, int t){
  if(t >= 52) return 0.f;
  int src;
  if(t<8){ int E = (q==0)?0:(8+8*q); src = E + t; }
  else if(t<30){ int d=t-8; int idx = 8*(d>>1)+2*q+(d&1);
                 src = (idx<8) ? (8+idx) : (32+idx); }
  else { int d=t-30; int idx = 8*(d>>1)+2*q+(d&1); src = 120+idx; }
  return m1[o*208 + src];
}
__device__ __forceinline__ float w1c_val(fp aw1, int o, int q, int h, int d){
  if(d >= 22) return 0.f;
  int idx = 8*(d>>1) + 2*q + (d&1);
  return h ? (aw1[o*264+176+idx] - aw1[o*264+88+idx])
           : (aw1[o*264+idx]     + aw1[o*264+88+idx]);
}

// lane q owns feature elements idx = 8r + 2q + e (r<11, e<2) of each 88-vec
__global__ void din_prep(fp aw1, fp ab1, fp aw2, fp ab2, fp aw3, fp ab3,
                         fp m1,  fp mb1, fp m2,  fp mb2, fp m3,  fp mb3,
                         fp m4,  fp mb4, float* __restrict__ ws){
  int j = blockIdx.x*blockDim.x + threadIdx.x;
  unsigned* wsu = (unsigned*)ws;
  if(j < 6144){ // W1C16 packed f16 pairs: [h][64 o][4 q][12 dw]
    int h = j/3072, r = j%3072;
    int slot = r/12, dw = r - slot*12;
    int o = slot>>2, q = slot&3;
    wsu[OFF_WC1H + j] = pack2h(w1c_val(aw1,o,q,h,2*dw), w1c_val(aw1,o,q,h,2*dw+1));
    return;
  } j -= 6144;
  if(j < 64){ ws[OFF_AB1 + j] = ab1[j]; return; } j -= 64;
  if(j < 1024){ // W2H: [32 pp][4 q][8 dw]; aw2 is [32 out][64 in]
    int pp = j>>5, q = (j>>3)&3, dw = j&7;
    int o = 8*q + dw;
    wsu[OFF_W2H + j] = pack2h(aw2[o*64 + 2*pp], aw2[o*64 + 2*pp+1]);
    return;
  } j -= 1024;
  if(j < 32){ ws[OFF_AB2 + j] = ab2[j]; return; } j -= 32;
  if(j < 32){ ws[OFF_W3  + j] = aw3[j]; return; } j -= 32;
  if(j < 1){ ws[OFF_AB3] = ab3[0]; return; } j -= 1;
  if(j < 64){ ws[OFF_MB2 + j] = mb2[j]; return; } j -= 64;
  if(j < 32){ ws[OFF_MB3 + j] = mb3[j]; return; } j -= 32;
  if(j < 32){ ws[OFF_M4  + j] = m4[j];  return; } j -= 32;
  if(j < 1){ ws[OFF_MB4] = mb4[0]; return; } j -= 1;
  if(j < 2){ ws[7426 + j] = 0.f; return; } j -= 2;  // pad
  if(j < 1024){ // M3H: [4 q][8 ip][32 dw]; m3 is [32 out][64 in]
    int qq = j>>8, rr = j&255, ip = rr>>5, dw = rr&31;
    wsu[OFF_M3H + j] = pack2h(m3[dw*64 + 16*qq + 2*ip], m3[dw*64 + 16*qq + 2*ip+1]);
    return;
  } j -= 1024;
  if(j < 14336){ // M1SH packed f16 pairs: [128 o][4 q][28 dw]
    int slot = j/28, dw = j - slot*28;
    int o = slot>>2, q = slot&3;
    wsu[OFF_M1H + j] = pack2h(m1s_val(m1,o,q,2*dw), m1s_val(m1,o,q,2*dw+1));
    return;
  } j -= 14336;
  if(j < 128){ ws[OFF_MB1 + j] = mb1[j]; return; } j -= 128;
  if(j < 4096){ // M2H: [64 gp][4 q][16 dw]; m2 is [64 out][128 in]
    int gp = j>>6, q = (j>>4)&3, dw = j&15;
    int o = 16*q + dw;
    wsu[OFF_M2H + j] = pack2h(m2[o*128 + 2*gp], m2[o*128 + 2*gp+1]);
    return;
  }
}

// DPP quad reduction: no LDS-pipe traffic
template<int CTL>
__device__ __forceinline__ float qp(float v){
  return __uint_as_float((unsigned)__builtin_amdgcn_update_dpp(
      0, (int)__float_as_uint(v), CTL, 0xF, 0xF, true));
}
__device__ __forceinline__ float bsum4(float v){
  v += qp<0xB1>(v);   // quad_perm [1,0,3,2]  (xor 1)
  v += qp<0x4E>(v);   // quad_perm [2,3,0,1]  (xor 2)
  return v;
}

// async global->LDS staging (dest wave-uniform base + lane*size; all staging
// dests are lane-linear within each wave)
__device__ __forceinline__ void ldst16(void* l, const void* g){
  __builtin_amdgcn_global_load_lds(
      (const __attribute__((address_space(1))) unsigned int*)(uintptr_t)g,
      (__attribute__((address_space(3))) unsigned int*)(uintptr_t)l, 16, 0, 0);
}
__device__ __forceinline__ void ldst4(void* l, const void* g){
  __builtin_amdgcn_global_load_lds(
      (const __attribute__((address_space(1))) unsigned int*)(uintptr_t)g,
      (__attribute__((address_space(3))) unsigned int*)(uintptr_t)l, 4, 0, 0);
}

// gather one 88-feature quad-slice as 11 packed f16 pairs
__device__ __forceinline__ void gather_h(const float2* __restrict__ itemp,
                                         const float2* __restrict__ kindp,
                                         int item_idx, const int* __restrict__ kidx,
                                         int q, v2h* f){
  float2 v = itemp[item_idx*4 + q];
  f[0] = pkh(v.x, v.y);
  #pragma unroll
  for(int r=0;r<KIND_LEN;r++){
    int ki = kidx[r];
    float2 w = kindp[ki*4 + q];
    float mx = ki ? w.x : 0.f, my = ki ? w.y : 0.f;
    f[1+r] = pkh(mx, my);
  }
}

// one history pass over NS steps; oo-pair loop: W1 rows from LDS f4[0,768),
// W2H pairs + tp pairs shared across steps; all accumulation f32.
template<int NS>
__device__ __forceinline__ void hist_pass(int b, int s0, int q, int wid,
    const float2* __restrict__ item_emb, const float2* __restrict__ kind_emb,
    const int* __restrict__ his_id, const int* __restrict__ his_kind,
    const float* ls, const float4* ls4, const unsigned* tpu, v2f* poolv){
  v2h i1h[NS][11];
  #pragma unroll
  for(int t=0;t<NS;t++)
    gather_h(item_emb, kind_emb, his_id[b*HIS_LEN + s0 + t],
             his_kind + (b*HIS_LEN + s0 + t)*KIND_LEN, q, i1h[t]);
  float h2s[NS][8];
  #pragma unroll
  for(int t=0;t<NS;t++)
    #pragma unroll
    for(int k=0;k<8;k++) h2s[t][k] = 0.f;

  #pragma unroll 1
  for(int p=0;p<32;p++){
    const uint4* wr0 = (const uint4*)(ls4 + ((2*p  )*4+q)*3);
    const uint4* wr1 = (const uint4*)(ls4 + ((2*p+1)*4+q)*3);
    uint4 r0=wr0[0], r1=wr0[1], r2=wr0[2];
    uint4 s0v=wr1[0], s1v=wr1[1], s2v=wr1[2];
    unsigned w0[12] = {r0.x,r0.y,r0.z,r0.w, r1.x,r1.y,r1.z,r1.w, r2.x,r2.y,r2.z,r2.w};
    unsigned w1[12] = {s0v.x,s0v.y,s0v.z,s0v.w, s1v.x,s1v.y,s1v.z,s1v.w, s2v.x,s2v.y,s2v.z,s2v.w};
    v2h t2 = C2H(tpu[p*SB + wid]);
    v2h hpv[NS];
    #pragma unroll
    for(int t=0;t<NS;t++){
      float aA=0.f, aB=0.f, cA=0.f, cB=0.f;
      #pragma unroll
      for(int u=0;u<11;u++){
        if(u&1){ aB = FD2(C2H(w0[u]), i1h[t][u], aB); cB = FD2(C2H(w1[u]), i1h[t][u], cB); }
        else   { aA = FD2(C2H(w0[u]), i1h[t][u], aA); cA = FD2(C2H(w1[u]), i1h[t][u], cA); }
      }
      float h0 = fmaxf(bsum4(aA+aB) + (float)t2.x, 0.f);
      float h1 = fmaxf(bsum4(cA+cB) + (float)t2.y, 0.f);
      hpv[t] = pkh(h0, h1);
    }
    uint4 wa = *(const uint4*)(ls4 + W2HF4 + (p*4+q)*2);
    uint4 wb = *(const uint4*)(ls4 + W2HF4 + (p*4+q)*2 + 1);
    unsigned w2d[8] = {wa.x,wa.y,wa.z,wa.w, wb.x,wb.y,wb.z,wb.w};
    #pragma unroll
    for(int t=0;t<NS;t++)
      #pragma unroll
      for(int k=0;k<8;k++) h2s[t][k] = FD2(C2H(w2d[k]), hpv[t], h2s[t][k]);
  }
  #pragma unroll
  for(int t=0;t<NS;t++){
    float scp = 0.f;
    #pragma unroll
    for(int j=0;j<8;j++){
      float hx = fmaxf(h2s[t][j] + ls[PFF+1088+8*q+j], 0.f);
      scp += ls[PFF+1120+8*q+j]*hx;
    }
    float sc = bsum4(scp) + ls[PFF+1152];
    #pragma unroll
    for(int j=0;j<11;j++){
      float sx = (float)i1h[t][j].x, sy = (float)i1h[t][j].y;
      poolv[j] = __builtin_elementwise_fma(mk2(sx*sc, sy*sc), mk2(sx, sy), poolv[j]);
    }
  }
}

__device__ __forceinline__ void mlp_stage(int c, int tid, float* ls, float4* ls4,
                                          const float* ws, const float4* ws4){
  int base = 768 + (c&1)*288;
  if(tid < 288){   // 224 f4 M1SH + 64 f4 M2H (chunk's 4 global pairs)
    const float4* src = (tid < 224) ? (ws4 + M1H4 + c*224 + tid)
                                    : (ws4 + M2H4 + c*64 + (tid-224));
    ldst16(ls4 + base + tid, src);
  }
  if(tid < 8) ldst4(ls + MBB + (c&1)*8 + tid, ws + OFF_MB1 + c*8 + tid);
}

// 512 threads; 128 samples/block; quad (q=lane&3) K-splits every dot.
__global__ void __launch_bounds__(NTH, 4)
din_main(const int* __restrict__ userid, const int* __restrict__ itemid,
         const int* __restrict__ age,    const int* __restrict__ gen,
         const int* __restrict__ occ,    const int* __restrict__ item_kind,
         const int* __restrict__ his_id, const int* __restrict__ his_kind,
         const float2* __restrict__ user_emb, const float2* __restrict__ item_emb,
         const float2* __restrict__ age_emb,  const float2* __restrict__ gen_emb,
         const float2* __restrict__ occ_emb,  const float2* __restrict__ kind_emb,
         const float* __restrict__ ws, float* __restrict__ out){
  const int tid  = threadIdx.x;
  const int q    = tid & 3;
  const int sl   = (tid & 63) >> 2;
  const int wv   = __builtin_amdgcn_readfirstlane(tid >> 6);
  const int wid  = wv*16 + sl;                 // sample-in-block 0..127
  const int b    = blockIdx.x*SB + wid;

  __shared__ __align__(16) float ls[LDSF];
  float4* ls4 = (float4*)ls;
  const float* wsc = ws;
  const float4* ws4 = (const float4*)ws;
  unsigned* tpu = (unsigned*)(ls + TPF);

  // ---- initial async staging: PF (1282 f) + W1C16 both halves (1536 f4) ----
  #pragma unroll
  for(int k=0;k<2;k++){ int j = k*NTH + tid; ldst4(ls + PFF + j, wsc + OFF_AB1 + j); }
  { int j = 2*NTH + tid;
    if(j < 1282) ldst4(ls + PFF + j, wsc + OFF_AB1 + j); }
  #pragma unroll
  for(int k=0;k<3;k++){ int j = k*NTH + tid; ldst16(ls4 + j, ws4 + j); }

  // ---- i2 slice as packed f16 (overlaps staging latency); lives all kernel ----
  v2h i2h[11];
  gather_h(item_emb, kind_emb, itemid[b], item_kind + b*KIND_LEN, q, i2h);

  __syncthreads();   // all staging drained

  // ---- phase A: t2+ab1 -> paired f16 tp (h=1 weights, f4 [768,1536)) ----
  // tp entries are written and later read by the SAME quad.
  #pragma unroll 1
  for(int p=0;p<32;p++){
    const uint4* wr0 = (const uint4*)(ls4 + 768 + ((2*p  )*4+q)*3);
    const uint4* wr1 = (const uint4*)(ls4 + 768 + ((2*p+1)*4+q)*3);
    uint4 r0=wr0[0], r1=wr0[1], r2=wr0[2];
    uint4 s0v=wr1[0], s1v=wr1[1], s2v=wr1[2];
    unsigned w0[12] = {r0.x,r0.y,r0.z,r0.w, r1.x,r1.y,r1.z,r1.w, r2.x,r2.y,r2.z,r2.w};
    unsigned w1[12] = {s0v.x,s0v.y,s0v.z,s0v.w, s1v.x,s1v.y,s1v.z,s1v.w, s2v.x,s2v.y,s2v.z,s2v.w};
    float aA=0.f, aB=0.f, cA=0.f, cB=0.f;
    #pragma unroll
    for(int u=0;u<11;u++){
      if(u&1){ aB = FD2(C2H(w0[u]), i2h[u], aB); cB = FD2(C2H(w1[u]), i2h[u], cB); }
      else   { aA = FD2(C2H(w0[u]), i2h[u], aA); cA = FD2(C2H(w1[u]), i2h[u], cA); }
    }
    float sA = bsum4(aA+aB), sB = bsum4(cA+cB);
    if(q==0){
      float2 bb = ((const float2*)(ls+PFF))[p];
      tpu[p*SB + wid] = __builtin_bit_cast(unsigned, pkh(sA+bb.x, sB+bb.y));
    }
  }

  __syncthreads();   // all waves done reading h=1 region

  // prefetch MLP chunks 0,1 into the (now free) h=1 region; history hides it
  mlp_stage(0, tid, ls, ls4, wsc, ws4);
  mlp_stage(1, tid, ls, ls4, wsc, ws4);

  // ---- history: 3 passes (2+2+1 steps), no barriers ----
  v2f poolv[11];
  #pragma unroll
  for(int d=0;d<11;d++) poolv[d]=mk2(0.f,0.f);
  hist_pass<2>(b, 0, q, wid, item_emb, kind_emb, his_id, his_kind, ls, ls4, tpu, poolv);
  hist_pass<2>(b, 2, q, wid, item_emb, kind_emb, his_id, his_kind, ls, ls4, tpu, poolv);
  hist_pass<1>(b, 4, q, wid, item_emb, kind_emb, his_id, his_kind, ls, ls4, tpu, poolv);

  // ---- MLP prologue: pack features, extras, init layer-2 accumulators ----
  v2h fe[26];
  {
    const float2* ep = (q==0)? user_emb : (q==1)? age_emb : (q==2)? gen_emb : occ_emb;
    int ei = (q==0)? userid[b] : (q==1)? age[b] : (q==2)? gen[b] : occ[b];
    #pragma unroll
    for(int k=0;k<4;k++){ float2 v = ep[ei*4+k]; fe[k] = pkh(v.x, v.y); }
  }
  #pragma unroll
  for(int j=0;j<11;j++) fe[4+j]  = i2h[j];
  #pragma unroll
  for(int j=0;j<11;j++) fe[15+j] = pkh(poolv[j].x, poolv[j].y);
  float h2s2[16];
  #pragma unroll
  for(int k=0;k<16;k++) h2s2[k] = ls[PFF+1153+16*q+k];

  __syncthreads();   // drains chunk 0,1 loads; aligns waves

  // ---- MLP layers 1+2: 16 chunks; i-paired layer-2 accumulate ----
  #pragma unroll 1
  for(int c=0;c<16;c++){
    int base = 768 + (c&1)*288;
    #pragma unroll 1
    for(int ii=0;ii<4;ii++){
      float hh[2];
      #pragma unroll
      for(int e=0;e<2;e++){
        int i = 2*ii + e;
        const uint4* wr = (const uint4*)(ls4 + base + (i*4+q)*7);
        unsigned dwv[28];
        #pragma unroll
        for(int k=0;k<7;k++){
          uint4 t = wr[k];
          dwv[4*k]=t.x; dwv[4*k+1]=t.y; dwv[4*k+2]=t.z; dwv[4*k+3]=t.w;
        }
        float aA = 0.f, aB = 0.f;
        #pragma unroll
        for(int u=0;u<26;u++){
          if(u&1) aB = FD2(C2H(dwv[u]), fe[u], aB);
          else    aA = FD2(C2H(dwv[u]), fe[u], aA);
        }
        hh[e] = fmaxf(bsum4(aA+aB) + ls[MBB + (c&1)*8 + i], 0.f);
      }
      v2h hp = pkh(hh[0], hh[1]);
      const uint4* w2p = (const uint4*)(ls4 + base + 224 + (ii*4+q)*4);
      uint4 a0=w2p[0], a1=w2p[1], a2=w2p[2], a3=w2p[3];
      unsigned d2[16] = {a0.x,a0.y,a0.z,a0.w, a1.x,a1.y,a1.z,a1.w,
                         a2.x,a2.y,a2.z,a2.w, a3.x,a3.y,a3.z,a3.w};
      #pragma unroll
      for(int k=0;k<16;k++) h2s2[k] = FD2(C2H(d2[k]), hp, h2s2[k]);
    }
    __syncthreads();          // all waves done with buf[c&1]; drains last stage
    if(c < 14){
      mlp_stage(c+2, tid, ls, ls4, wsc, ws4);   // into buf[c&1], 2 ahead
    } else if(c == 14){
      // tail: stage M3H skewed (q-stripe at f4 q*66) into h0 region f4[0,262)
      if(tid < 256) ldst16(ls4 + (tid>>6)*66 + (tid&63), ws4 + M3H4 + tid);
    }
  }
  // c==15's loop-end barrier drained the M3H loads

  // ---- tail: layers 3+4, i-paired fdot2 ----
  v2h hp3[8];
  #pragma unroll
  for(int ip=0;ip<8;ip++)
    hp3[ip] = pkh(fmaxf(h2s2[2*ip],0.f), fmaxf(h2s2[2*ip+1],0.f));

  float x = ls[PFF+1281];
  #pragma unroll
  for(int g=0;g<4;g++){
    float a[8];
    #pragma unroll
    for(int j=0;j<8;j++) a[j]=0.f;
    #pragma unroll
    for(int ip=0;ip<8;ip++){
      const uint4* w3p = (const uint4*)(ls4 + q*66 + ip*8 + 2*g);
      uint4 b0=w3p[0], b1=w3p[1];
      a[0]=FD2(C2H(b0.x),hp3[ip],a[0]); a[1]=FD2(C2H(b0.y),hp3[ip],a[1]);
      a[2]=FD2(C2H(b0.z),hp3[ip],a[2]); a[3]=FD2(C2H(b0.w),hp3[ip],a[3]);
      a[4]=FD2(C2H(b1.x),hp3[ip],a[4]); a[5]=FD2(C2H(b1.y),hp3[ip],a[5]);
      a[6]=FD2(C2H(b1.z),hp3[ip],a[6]); a[7]=FD2(C2H(b1.w),hp3[ip],a[7]);
    }
    #pragma unroll
    for(int j=0;j<8;j++) a[j] = bsum4(a[j]);
    #pragma unroll
    for(int j=0;j<8;j++)
      x += ls[PFF+1249+8*g+j] * fmaxf(a[j] + ls[PFF+1217+8*g+j], 0.f);
  }

  if(q==0) out[b] = 1.0f/(1.0f + __expf(-x));
}

extern "C" void kernel_launch(void* const* d_in, const int* in_sizes, int n_in,
                              void* d_out, int out_size, void* d_ws, size_t ws_size,
                              hipStream_t stream){
  const int* userid    = (const int*)d_in[0];
  const int* itemid    = (const int*)d_in[1];
  const int* age       = (const int*)d_in[2];
  const int* gen       = (const int*)d_in[3];
  const int* occ       = (const int*)d_in[4];
  const int* item_kind = (const int*)d_in[5];
  const int* his_id    = (const int*)d_in[6];
  const int* his_kind  = (const int*)d_in[7];
  const float2* user_emb = (const float2*)d_in[8];
  const float2* item_emb = (const float2*)d_in[9];
  const float2* age_emb  = (const float2*)d_in[10];
  const float2* gen_emb  = (const float2*)d_in[11];
  const float2* occ_emb  = (const float2*)d_in[12];
  const float2* kind_emb = (const float2*)d_in[13];
  float* ws = (float*)d_ws;

  din_prep<<<(PREP_N+255)/256, 256, 0, stream>>>(
      (fp)d_in[14], (fp)d_in[15], (fp)d_in[16], (fp)d_in[17], (fp)d_in[18], (fp)d_in[19],
      (fp)d_in[20], (fp)d_in[21], (fp)d_in[22], (fp)d_in[23], (fp)d_in[24], (fp)d_in[25],
      (fp)d_in[26], (fp)d_in[27], ws);

  din_main<<<BATCH/SB, NTH, 0, stream>>>(
      userid, itemid, age, gen, occ, item_kind, his_id, his_kind,
      user_emb, item_emb, age_emb, gen_emb, occ_emb, kind_emb,
      ws, (float*)d_out);
}

// Round 9
// 284.018 us; speedup vs baseline: 2.6361x; 1.0048x over previous
//
#include <hip/hip_runtime.h>
#include <cstdint>
#include <math.h>

#define BATCH    65536
#define HIS_LEN  5
#define KIND_LEN 10
#define SB       64    // samples per block
#define NTH      256   // threads per block (4 waves); 4 threads per sample

typedef float    v2f __attribute__((ext_vector_type(2)));
typedef _Float16 v2h __attribute__((ext_vector_type(2)));
__device__ __forceinline__ v2f mk2(float a, float b){ v2f r; r.x=a; r.y=b; return r; }
#define C2H(u) __builtin_bit_cast(v2h,(unsigned)(u))

#if __has_builtin(__builtin_amdgcn_fdot2)
__device__ __forceinline__ float FD2(v2h a, v2h b, float c){
  return __builtin_amdgcn_fdot2(a, b, c, false);   // v_dot2_f32_f16
}
#else
__device__ __forceinline__ float FD2(v2h a, v2h b, float c){
  return c + (float)a.x*(float)b.x + (float)a.y*(float)b.y;
}
#endif

__device__ __forceinline__ unsigned short f2h(float f){
  return __builtin_bit_cast(unsigned short, (_Float16)f);
}
__device__ __forceinline__ unsigned pack2h(float a, float b){
  return (unsigned)f2h(a) | ((unsigned)f2h(b) << 16);
}
__device__ __forceinline__ v2h pkh(float a, float b){
  return __builtin_bit_cast(v2h, __builtin_amdgcn_cvt_pkrtz(a, b));
}

// ---- ws layout (dword offsets) ----
#define OFF_WC1H 0      // 6144  f16x2: [h][64 o][4 q][12 dw] (22 data + 2 pad)
#define OFF_AB1  6144   // 64    f32
#define OFF_W2H  6208   // 1024  f16x2 pairs: [32 pp][4 q][8 dw]; dw j -> out 8q+j, pair (2pp,2pp+1)
#define OFF_AB2  7232   // 32
#define OFF_W3   7264   // 32
#define OFF_AB3  7296   // 1
#define OFF_MB2  7297   // 64
#define OFF_MB3  7361   // 32
#define OFF_M4   7393   // 32
#define OFF_MB4  7425   // 1   -> PF block ws[6144,7426) = 1282 floats
#define OFF_M3H  7428   // 1024 f16x2 pairs: [4 q][8 ip][32 dw]; dw=out, pair in=(16q+2ip,+1)
#define OFF_M1H  8452   // 14336 f16x2: [128 o][4 q][28 dw] (52 data + 4 pad)
#define OFF_MB1  22788  // 128
#define OFF_M2H  22916  // 4096 f16x2 pairs: [64 gp][4 q][16 dw]; dw k -> out 16q+k, pair in=(2gp,2gp+1)
#define PREP_N   27012
// f4 indices into ws
#define M1H4  2113      // 8452/4
#define M2H4  5729      // 22916/4
#define M3H4  1857      // 7428/4

// ---- LDS float layout ----
//  f4 [0,768):    W1C16 h=0 (history); tail reuses for skewed M3H (f4 [0,262))
//  f4 [768,1536): W1C16 h=1 (phase A); then two 288-f4 MLP chunk bufs [768,1344)
//  [6144,7426):   PF = AB1(64)|W2H(1024dw)|AB2(32)|W3(32)|AB3(1)|MB2(64)|MB3(32)|M4(32)|MB4(1)
//  [7426,7442):   MLP bias double-slot (8 per chunk parity)
//  [7442,9490):   tp: 2048 dwords = 32 oo-pairs x 64 samples (f16 pair: t2+ab1)
#define PFF   6144
#define W2HF4 1552      // (PFF+64)/4
#define MBB   7426
#define TPF   7442
#define LDSF  9490

typedef const float* fp;

__device__ __forceinline__ float m1s_val(fp m1, int o, int q, int t){
  if(t >= 52) return 0.f;
  int src;
  if(t<8){ int E = (q==0)?0:(8+8*q); src = E + t; }
  else if(t<30){ int d=t-8; int idx = 8*(d>>1)+2*q+(d&1);
                 src = (idx<8) ? (8+idx) : (32+idx); }
  else { int d=t-30; int idx = 8*(d>>1)+2*q+(d&1); src = 120+idx; }
  return m1[o*208 + src];
}
__device__ __forceinline__ float w1c_val(fp aw1, int o, int q, int h, int d){
  if(d >= 22) return 0.f;
  int idx = 8*(d>>1) + 2*q + (d&1);
  return h ? (aw1[o*264+176+idx] - aw1[o*264+88+idx])
           : (aw1[o*264+idx]     + aw1[o*264+88+idx]);
}

// lane q owns feature elements idx = 8r + 2q + e (r<11, e<2) of each 88-vec
__global__ void din_prep(fp aw1, fp ab1, fp aw2, fp ab2, fp aw3, fp ab3,
                         fp m1,  fp mb1, fp m2,  fp mb2, fp m3,  fp mb3,
                         fp m4,  fp mb4, float* __restrict__ ws){
  int j = blockIdx.x*blockDim.x + threadIdx.x;
  unsigned* wsu = (unsigned*)ws;
  if(j < 6144){ // W1C16 packed f16 pairs: [h][64 o][4 q][12 dw]
    int h = j/3072, r = j%3072;
    int slot = r/12, dw = r - slot*12;
    int o = slot>>2, q = slot&3;
    wsu[OFF_WC1H + j] = pack2h(w1c_val(aw1,o,q,h,2*dw), w1c_val(aw1,o,q,h,2*dw+1));
    return;
  } j -= 6144;
  if(j < 64){ ws[OFF_AB1 + j] = ab1[j]; return; } j -= 64;
  if(j < 1024){ // W2H: [32 pp][4 q][8 dw]; aw2 is [32 out][64 in]
    int pp = j>>5, q = (j>>3)&3, dw = j&7;
    int o = 8*q + dw;
    wsu[OFF_W2H + j] = pack2h(aw2[o*64 + 2*pp], aw2[o*64 + 2*pp+1]);
    return;
  } j -= 1024;
  if(j < 32){ ws[OFF_AB2 + j] = ab2[j]; return; } j -= 32;
  if(j < 32){ ws[OFF_W3  + j] = aw3[j]; return; } j -= 32;
  if(j < 1){ ws[OFF_AB3] = ab3[0]; return; } j -= 1;
  if(j < 64){ ws[OFF_MB2 + j] = mb2[j]; return; } j -= 64;
  if(j < 32){ ws[OFF_MB3 + j] = mb3[j]; return; } j -= 32;
  if(j < 32){ ws[OFF_M4  + j] = m4[j];  return; } j -= 32;
  if(j < 1){ ws[OFF_MB4] = mb4[0]; return; } j -= 1;
  if(j < 2){ ws[7426 + j] = 0.f; return; } j -= 2;  // pad
  if(j < 1024){ // M3H: [4 q][8 ip][32 dw]; m3 is [32 out][64 in]
    int qq = j>>8, rr = j&255, ip = rr>>5, dw = rr&31;
    wsu[OFF_M3H + j] = pack2h(m3[dw*64 + 16*qq + 2*ip], m3[dw*64 + 16*qq + 2*ip+1]);
    return;
  } j -= 1024;
  if(j < 14336){ // M1SH packed f16 pairs: [128 o][4 q][28 dw]
    int slot = j/28, dw = j - slot*28;
    int o = slot>>2, q = slot&3;
    wsu[OFF_M1H + j] = pack2h(m1s_val(m1,o,q,2*dw), m1s_val(m1,o,q,2*dw+1));
    return;
  } j -= 14336;
  if(j < 128){ ws[OFF_MB1 + j] = mb1[j]; return; } j -= 128;
  if(j < 4096){ // M2H: [64 gp][4 q][16 dw]; m2 is [64 out][128 in]
    int gp = j>>6, q = (j>>4)&3, dw = j&15;
    int o = 16*q + dw;
    wsu[OFF_M2H + j] = pack2h(m2[o*128 + 2*gp], m2[o*128 + 2*gp+1]);
    return;
  }
}

// DPP quad reduction: no LDS-pipe traffic
template<int CTL>
__device__ __forceinline__ float qp(float v){
  return __uint_as_float((unsigned)__builtin_amdgcn_update_dpp(
      0, (int)__float_as_uint(v), CTL, 0xF, 0xF, true));
}
__device__ __forceinline__ float bsum4(float v){
  v += qp<0xB1>(v);   // quad_perm [1,0,3,2]  (xor 1)
  v += qp<0x4E>(v);   // quad_perm [2,3,0,1]  (xor 2)
  return v;
}

// async global->LDS staging (dest wave-uniform base + lane*size; all staging
// dests are lane-linear within each wave)
__device__ __forceinline__ void ldst16(void* l, const void* g){
  __builtin_amdgcn_global_load_lds(
      (const __attribute__((address_space(1))) unsigned int*)(uintptr_t)g,
      (__attribute__((address_space(3))) unsigned int*)(uintptr_t)l, 16, 0, 0);
}
__device__ __forceinline__ void ldst4(void* l, const void* g){
  __builtin_amdgcn_global_load_lds(
      (const __attribute__((address_space(1))) unsigned int*)(uintptr_t)g,
      (__attribute__((address_space(3))) unsigned int*)(uintptr_t)l, 4, 0, 0);
}

// gather one 88-feature quad-slice as 11 packed f16 pairs
__device__ __forceinline__ void gather_h(const float2* __restrict__ itemp,
                                         const float2* __restrict__ kindp,
                                         int item_idx, const int* __restrict__ kidx,
                                         int q, v2h* f){
  float2 v = itemp[item_idx*4 + q];
  f[0] = pkh(v.x, v.y);
  #pragma unroll
  for(int r=0;r<KIND_LEN;r++){
    int ki = kidx[r];
    float2 w = kindp[ki*4 + q];
    float mx = ki ? w.x : 0.f, my = ki ? w.y : 0.f;
    f[1+r] = pkh(mx, my);
  }
}

// one history pass over NS steps; oo-pair loop: W1 rows from LDS f4[0,768),
// W2H pairs + tp pairs shared across steps; all accumulation f32.
template<int NS>
__device__ __forceinline__ void hist_pass(int b, int s0, int q, int wid,
    const float2* __restrict__ item_emb, const float2* __restrict__ kind_emb,
    const int* __restrict__ his_id, const int* __restrict__ his_kind,
    const float* ls, const float4* ls4, const unsigned* tpu, v2f* poolv){
  v2h i1h[NS][11];
  #pragma unroll
  for(int t=0;t<NS;t++)
    gather_h(item_emb, kind_emb, his_id[b*HIS_LEN + s0 + t],
             his_kind + (b*HIS_LEN + s0 + t)*KIND_LEN, q, i1h[t]);
  float h2s[NS][8];
  #pragma unroll
  for(int t=0;t<NS;t++)
    #pragma unroll
    for(int k=0;k<8;k++) h2s[t][k] = 0.f;

  #pragma unroll 1
  for(int p=0;p<32;p++){
    const uint4* wr0 = (const uint4*)(ls4 + ((2*p  )*4+q)*3);
    const uint4* wr1 = (const uint4*)(ls4 + ((2*p+1)*4+q)*3);
    uint4 r0=wr0[0], r1=wr0[1], r2=wr0[2];
    uint4 s0v=wr1[0], s1v=wr1[1], s2v=wr1[2];
    unsigned w0[12] = {r0.x,r0.y,r0.z,r0.w, r1.x,r1.y,r1.z,r1.w, r2.x,r2.y,r2.z,r2.w};
    unsigned w1[12] = {s0v.x,s0v.y,s0v.z,s0v.w, s1v.x,s1v.y,s1v.z,s1v.w, s2v.x,s2v.y,s2v.z,s2v.w};
    v2h t2 = C2H(tpu[p*SB + wid]);
    v2h hpv[NS];
    #pragma unroll
    for(int t=0;t<NS;t++){
      float aA=0.f, aB=0.f, cA=0.f, cB=0.f;
      #pragma unroll
      for(int u=0;u<11;u++){
        if(u&1){ aB = FD2(C2H(w0[u]), i1h[t][u], aB); cB = FD2(C2H(w1[u]), i1h[t][u], cB); }
        else   { aA = FD2(C2H(w0[u]), i1h[t][u], aA); cA = FD2(C2H(w1[u]), i1h[t][u], cA); }
      }
      float h0 = fmaxf(bsum4(aA+aB) + (float)t2.x, 0.f);
      float h1 = fmaxf(bsum4(cA+cB) + (float)t2.y, 0.f);
      hpv[t] = pkh(h0, h1);
    }
    uint4 wa = *(const uint4*)(ls4 + W2HF4 + (p*4+q)*2);
    uint4 wb = *(const uint4*)(ls4 + W2HF4 + (p*4+q)*2 + 1);
    unsigned w2d[8] = {wa.x,wa.y,wa.z,wa.w, wb.x,wb.y,wb.z,wb.w};
    #pragma unroll
    for(int t=0;t<NS;t++)
      #pragma unroll
      for(int k=0;k<8;k++) h2s[t][k] = FD2(C2H(w2d[k]), hpv[t], h2s[t][k]);
  }
  #pragma unroll
  for(int t=0;t<NS;t++){
    float scp = 0.f;
    #pragma unroll
    for(int j=0;j<8;j++){
      float hx = fmaxf(h2s[t][j] + ls[PFF+1088+8*q+j], 0.f);
      scp += ls[PFF+1120+8*q+j]*hx;
    }
    float sc = bsum4(scp) + ls[PFF+1152];
    #pragma unroll
    for(int j=0;j<11;j++){
      float sx = (float)i1h[t][j].x, sy = (float)i1h[t][j].y;
      poolv[j] = __builtin_elementwise_fma(mk2(sx*sc, sy*sc), mk2(sx, sy), poolv[j]);
    }
  }
}

__device__ __forceinline__ void mlp_stage(int c, int tid, float* ls, float4* ls4,
                                          const float* ws, const float4* ws4){
  int base = 768 + (c&1)*288;
  {  // 288 f4: 224 M1SH + 64 M2H; dest = base + j, lane-linear per wave
    const float4* src = (tid < 224) ? (ws4 + M1H4 + c*224 + tid)
                                    : (ws4 + M2H4 + c*64 + (tid-224));
    ldst16(ls4 + base + tid, src);
    if(tid < 32) ldst16(ls4 + base + 256 + tid, ws4 + M2H4 + c*64 + 32 + tid);
  }
  if(tid < 8) ldst4(ls + MBB + (c&1)*8 + tid, ws + OFF_MB1 + c*8 + tid);
}

// 256 threads; 64 samples/block; quad (q=lane&3) K-splits every dot.
// 4 blocks/CU desynchronize barrier stalls (vs 2 blocks of 8 waves).
__global__ void __launch_bounds__(NTH, 4)
din_main(const int* __restrict__ userid, const int* __restrict__ itemid,
         const int* __restrict__ age,    const int* __restrict__ gen,
         const int* __restrict__ occ,    const int* __restrict__ item_kind,
         const int* __restrict__ his_id, const int* __restrict__ his_kind,
         const float2* __restrict__ user_emb, const float2* __restrict__ item_emb,
         const float2* __restrict__ age_emb,  const float2* __restrict__ gen_emb,
         const float2* __restrict__ occ_emb,  const float2* __restrict__ kind_emb,
         const float* __restrict__ ws, float* __restrict__ out){
  const int tid  = threadIdx.x;
  const int q    = tid & 3;
  const int sl   = (tid & 63) >> 2;
  const int wv   = __builtin_amdgcn_readfirstlane(tid >> 6);
  const int wid  = wv*16 + sl;                 // sample-in-block 0..63
  const int b    = blockIdx.x*SB + wid;

  __shared__ __align__(16) float ls[LDSF];
  float4* ls4 = (float4*)ls;
  const float* wsc = ws;
  const float4* ws4 = (const float4*)ws;
  unsigned* tpu = (unsigned*)(ls + TPF);

  // ---- initial async staging: PF (1282 f) + W1C16 both halves (1536 f4) ----
  #pragma unroll
  for(int k=0;k<5;k++){ int j = k*NTH + tid; ldst4(ls + PFF + j, wsc + OFF_AB1 + j); }
  { int j = 5*NTH + tid;
    if(j < 1282) ldst4(ls + PFF + j, wsc + OFF_AB1 + j); }
  #pragma unroll
  for(int k=0;k<6;k++){ int j = k*NTH + tid; ldst16(ls4 + j, ws4 + j); }

  // ---- i2 slice as packed f16 (overlaps staging latency); lives all kernel ----
  v2h i2h[11];
  gather_h(item_emb, kind_emb, itemid[b], item_kind + b*KIND_LEN, q, i2h);

  __syncthreads();   // all staging drained

  // ---- phase A: t2+ab1 -> paired f16 tp (h=1 weights, f4 [768,1536)) ----
  // tp entries are written and later read by the SAME quad.
  #pragma unroll 1
  for(int p=0;p<32;p++){
    const uint4* wr0 = (const uint4*)(ls4 + 768 + ((2*p  )*4+q)*3);
    const uint4* wr1 = (const uint4*)(ls4 + 768 + ((2*p+1)*4+q)*3);
    uint4 r0=wr0[0], r1=wr0[1], r2=wr0[2];
    uint4 s0v=wr1[0], s1v=wr1[1], s2v=wr1[2];
    unsigned w0[12] = {r0.x,r0.y,r0.z,r0.w, r1.x,r1.y,r1.z,r1.w, r2.x,r2.y,r2.z,r2.w};
    unsigned w1[12] = {s0v.x,s0v.y,s0v.z,s0v.w, s1v.x,s1v.y,s1v.z,s1v.w, s2v.x,s2v.y,s2v.z,s2v.w};
    float aA=0.f, aB=0.f, cA=0.f, cB=0.f;
    #pragma unroll
    for(int u=0;u<11;u++){
      if(u&1){ aB = FD2(C2H(w0[u]), i2h[u], aB); cB = FD2(C2H(w1[u]), i2h[u], cB); }
      else   { aA = FD2(C2H(w0[u]), i2h[u], aA); cA = FD2(C2H(w1[u]), i2h[u], cA); }
    }
    float sA = bsum4(aA+aB), sB = bsum4(cA+cB);
    if(q==0){
      float2 bb = ((const float2*)(ls+PFF))[p];
      tpu[p*SB + wid] = __builtin_bit_cast(unsigned, pkh(sA+bb.x, sB+bb.y));
    }
  }

  __syncthreads();   // all waves done reading h=1 region

  // prefetch MLP chunks 0,1 into the (now free) h=1 region; history hides it
  mlp_stage(0, tid, ls, ls4, wsc, ws4);
  mlp_stage(1, tid, ls, ls4, wsc, ws4);

  // ---- history: 3 passes (2+2+1 steps), no barriers ----
  v2f poolv[11];
  #pragma unroll
  for(int d=0;d<11;d++) poolv[d]=mk2(0.f,0.f);
  hist_pass<2>(b, 0, q, wid, item_emb, kind_emb, his_id, his_kind, ls, ls4, tpu, poolv);
  hist_pass<2>(b, 2, q, wid, item_emb, kind_emb, his_id, his_kind, ls, ls4, tpu, poolv);
  hist_pass<1>(b, 4, q, wid, item_emb, kind_emb, his_id, his_kind, ls, ls4, tpu, poolv);

  // ---- MLP prologue: pack features, extras, init layer-2 accumulators ----
  v2h fe[26];
  {
    const float2* ep = (q==0)? user_emb : (q==1)? age_emb : (q==2)? gen_emb : occ_emb;
    int ei = (q==0)? userid[b] : (q==1)? age[b] : (q==2)? gen[b] : occ[b];
    #pragma unroll
    for(int k=0;k<4;k++){ float2 v = ep[ei*4+k]; fe[k] = pkh(v.x, v.y); }
  }
  #pragma unroll
  for(int j=0;j<11;j++) fe[4+j]  = i2h[j];
  #pragma unroll
  for(int j=0;j<11;j++) fe[15+j] = pkh(poolv[j].x, poolv[j].y);
  float h2s2[16];
  #pragma unroll
  for(int k=0;k<16;k++) h2s2[k] = ls[PFF+1153+16*q+k];

  __syncthreads();   // drains chunk 0,1 loads; aligns waves

  // ---- MLP layers 1+2: 16 chunks; i-paired layer-2 accumulate ----
  #pragma unroll 1
  for(int c=0;c<16;c++){
    int base = 768 + (c&1)*288;
    #pragma unroll 1
    for(int ii=0;ii<4;ii++){
      float hh[2];
      #pragma unroll
      for(int e=0;e<2;e++){
        int i = 2*ii + e;
        const uint4* wr = (const uint4*)(ls4 + base + (i*4+q)*7);
        unsigned dwv[28];
        #pragma unroll
        for(int k=0;k<7;k++){
          uint4 t = wr[k];
          dwv[4*k]=t.x; dwv[4*k+1]=t.y; dwv[4*k+2]=t.z; dwv[4*k+3]=t.w;
        }
        float aA = 0.f, aB = 0.f;
        #pragma unroll
        for(int u=0;u<26;u++){
          if(u&1) aB = FD2(C2H(dwv[u]), fe[u], aB);
          else    aA = FD2(C2H(dwv[u]), fe[u], aA);
        }
        hh[e] = fmaxf(bsum4(aA+aB) + ls[MBB + (c&1)*8 + i], 0.f);
      }
      v2h hp = pkh(hh[0], hh[1]);
      const uint4* w2p = (const uint4*)(ls4 + base + 224 + (ii*4+q)*4);
      uint4 a0=w2p[0], a1=w2p[1], a2=w2p[2], a3=w2p[3];
      unsigned d2[16] = {a0.x,a0.y,a0.z,a0.w, a1.x,a1.y,a1.z,a1.w,
                         a2.x,a2.y,a2.z,a2.w, a3.x,a3.y,a3.z,a3.w};
      #pragma unroll
      for(int k=0;k<16;k++) h2s2[k] = FD2(C2H(d2[k]), hp, h2s2[k]);
    }
    __syncthreads();          // all waves done with buf[c&1]; drains last stage
    if(c < 14){
      mlp_stage(c+2, tid, ls, ls4, wsc, ws4);   // into buf[c&1], 2 ahead
    } else if(c == 14){
      // tail: stage M3H skewed (q-stripe at f4 q*66) into h0 region f4[0,262)
      ldst16(ls4 + (tid>>6)*66 + (tid&63), ws4 + M3H4 + tid);
    }
  }
  // c==15's loop-end barrier drained the M3H loads

  // ---- tail: layers 3+4, i-paired fdot2 ----
  v2h hp3[8];
  #pragma unroll
  for(int ip=0;ip<8;ip++)
    hp3[ip] = pkh(fmaxf(h2s2[2*ip],0.f), fmaxf(h2s2[2*ip+1],0.f));

  float x = ls[PFF+1281];
  #pragma unroll
  for(int g=0;g<4;g++){
    float a[8];
    #pragma unroll
    for(int j=0;j<8;j++) a[j]=0.f;
    #pragma unroll
    for(int ip=0;ip<8;ip++){
      const uint4* w3p = (const uint4*)(ls4 + q*66 + ip*8 + 2*g);
      uint4 b0=w3p[0], b1=w3p[1];
      a[0]=FD2(C2H(b0.x),hp3[ip],a[0]); a[1]=FD2(C2H(b0.y),hp3[ip],a[1]);
      a[2]=FD2(C2H(b0.z),hp3[ip],a[2]); a[3]=FD2(C2H(b0.w),hp3[ip],a[3]);
      a[4]=FD2(C2H(b1.x),hp3[ip],a[4]); a[5]=FD2(C2H(b1.y),hp3[ip],a[5]);
      a[6]=FD2(C2H(b1.z),hp3[ip],a[6]); a[7]=FD2(C2H(b1.w),hp3[ip],a[7]);
    }
    #pragma unroll
    for(int j=0;j<8;j++) a[j] = bsum4(a[j]);
    #pragma unroll
    for(int j=0;j<8;j++)
      x += ls[PFF+1249+8*g+j] * fmaxf(a[j] + ls[PFF+1217+8*g+j], 0.f);
  }

  if(q==0) out[b] = 1.0f/(1.0f + __expf(-x));
}

extern "C" void kernel_launch(void* const* d_in, const int* in_sizes, int n_in,
                              void* d_out, int out_size, void* d_ws, size_t ws_size,
                              hipStream_t stream){
  const int* userid    = (const int*)d_in[0];
  const int* itemid    = (const int*)d_in[1];
  const int* age       = (const int*)d_in[2];
  const int* gen       = (const int*)d_in[3];
  const int* occ       = (const int*)d_in[4];
  const int* item_kind = (const int*)d_in[5];
  const int* his_id    = (const int*)d_in[6];
  const int* his_kind  = (const int*)d_in[7];
  const float2* user_emb = (const float2*)d_in[8];
  const float2* item_emb = (const float2*)d_in[9];
  const float2* age_emb  = (const float2*)d_in[10];
  const float2* gen_emb  = (const float2*)d_in[11];
  const float2* occ_emb  = (const float2*)d_in[12];
  const float2* kind_emb = (const float2*)d_in[13];
  float* ws = (float*)d_ws;

  din_prep<<<(PREP_N+255)/256, 256, 0, stream>>>(
      (fp)d_in[14], (fp)d_in[15], (fp)d_in[16], (fp)d_in[17], (fp)d_in[18], (fp)d_in[19],
      (fp)d_in[20], (fp)d_in[21], (fp)d_in[22], (fp)d_in[23], (fp)d_in[24], (fp)d_in[25],
      (fp)d_in[26], (fp)d_in[27], ws);

  din_main<<<BATCH/SB, NTH, 0, stream>>>(
      userid, itemid, age, gen, occ, item_kind, his_id, his_kind,
      user_emb, item_emb, age_emb, gen_emb, occ_emb, kind_emb,
      ws, (float*)d_out);
}

// Round 10
// 242.198 us; speedup vs baseline: 3.0913x; 1.1727x over previous
//
#include <hip/hip_runtime.h>
#include <cstdint>
#include <math.h>

#define BATCH    65536
#define HIS_LEN  5
#define KIND_LEN 10
#define SB       64    // samples per block
#define NTH      256   // threads per block (4 waves); 4 threads per sample

typedef float    v2f __attribute__((ext_vector_type(2)));
typedef float    v4f __attribute__((ext_vector_type(4)));
typedef _Float16 v2h __attribute__((ext_vector_type(2)));
typedef _Float16 v8h __attribute__((ext_vector_type(8)));
__device__ __forceinline__ v2f mk2(float a, float b){ v2f r; r.x=a; r.y=b; return r; }
#define C2H(u)  __builtin_bit_cast(v2h,(unsigned)(u))
#define C8H(u4) __builtin_bit_cast(v8h,(u4))

#if __has_builtin(__builtin_amdgcn_fdot2)
__device__ __forceinline__ float FD2(v2h a, v2h b, float c){
  return __builtin_amdgcn_fdot2(a, b, c, false);   // v_dot2_f32_f16
}
#else
__device__ __forceinline__ float FD2(v2h a, v2h b, float c){
  return c + (float)a.x*(float)b.x + (float)a.y*(float)b.y;
}
#endif

__device__ __forceinline__ unsigned short f2h(float f){
  return __builtin_bit_cast(unsigned short, (_Float16)f);
}
__device__ __forceinline__ unsigned pack2h(float a, float b){
  return (unsigned)f2h(a) | ((unsigned)f2h(b) << 16);
}
__device__ __forceinline__ v2h pkh(float a, float b){
  return __builtin_bit_cast(v2h, __builtin_amdgcn_cvt_pkrtz(a, b));
}

// ---- ws layout (dword offsets) ----
#define OFF_WC1H 0      // 6144  f16x2: [h][64 o][4 q][12 dw]
#define OFF_AB1  6144   // 64
#define OFF_W2H  6208   // 1024  f16x2 pairs: [32 pp][4 q][8 dw]
#define OFF_AB2  7232   // 32
#define OFF_W3   7264   // 32
#define OFF_AB3  7296   // 1
#define OFF_MB2  7297   // 64
#define OFF_MB3  7361   // 32
#define OFF_M4   7393   // 32
#define OFF_MB4  7425   // 1   -> PF block ws[6144,7426) = 1282 floats
#define OFF_M3H  7428   // 1024 f16x2 pairs: [4 q][8 ip][32 dw]
#define OFF_W1F  8452   // 14336 dw: MFMA B-frags [8 n][7 t][64 lane][4 dw]
#define OFF_MB1  22788  // 128
#define OFF_W2F  22916  // 4096 dw: MFMA B-frags [4 n2][4 t2][64 lane][4 dw]
#define PREP_N   27012
// f4 indices into ws
#define W1F4  2113      // 8452/4
#define W2F4  5729      // 22916/4
#define M3H4  1857      // 7428/4

// ---- LDS float layout ----
//  f4 [0,1536):   W1C16 h0 [0,768) + h1 [768,1536)  (phase A / history)
//  f [6144,8192): tp 2048 dw (phase A -> history)
//  after history: X matrix f4 [0,1856) (64 rows x 29 f4, k-order [q][56])
//  after A-frag load: H1 f16 f4 [0,1088) (row stride 17 f4) ; H2 f16 f4 [1088,1664)
//  M3H (tail weights) f4 [1856,2118)
//  PF  f [8704,9986) ; MB1 f [9986,10114)
#define TPF   6144
#define M3HL  1856      // f4
#define PFF   8704
#define W2HF4 2192      // (PFF+64)/4
#define MB1F  9986
#define H2F4  1088
#define LDSF  10114

typedef const float* fp;

__device__ __forceinline__ float m1s_val(fp m1, int o, int q, int t){
  if(t >= 52) return 0.f;
  int src;
  if(t<8){ int E = (q==0)?0:(8+8*q); src = E + t; }
  else if(t<30){ int d=t-8; int idx = 8*(d>>1)+2*q+(d&1);
                 src = (idx<8) ? (8+idx) : (32+idx); }
  else { int d=t-30; int idx = 8*(d>>1)+2*q+(d&1); src = 120+idx; }
  return m1[o*208 + src];
}
__device__ __forceinline__ float m1k(fp m1, int o, int k){   // k in [0,224)
  return m1s_val(m1, o, k/56, k%56);
}
__device__ __forceinline__ float w1c_val(fp aw1, int o, int q, int h, int d){
  if(d >= 22) return 0.f;
  int idx = 8*(d>>1) + 2*q + (d&1);
  return h ? (aw1[o*264+176+idx] - aw1[o*264+88+idx])
           : (aw1[o*264+idx]     + aw1[o*264+88+idx]);
}

// lane q owns feature elements idx = 8r + 2q + e (r<11, e<2) of each 88-vec
__global__ void din_prep(fp aw1, fp ab1, fp aw2, fp ab2, fp aw3, fp ab3,
                         fp m1,  fp mb1, fp m2,  fp mb2, fp m3,  fp mb3,
                         fp m4,  fp mb4, float* __restrict__ ws){
  int j = blockIdx.x*blockDim.x + threadIdx.x;
  unsigned* wsu = (unsigned*)ws;
  if(j < 6144){ // W1C16 packed f16 pairs: [h][64 o][4 q][12 dw]
    int h = j/3072, r = j%3072;
    int slot = r/12, dw = r - slot*12;
    int o = slot>>2, q = slot&3;
    wsu[OFF_WC1H + j] = pack2h(w1c_val(aw1,o,q,h,2*dw), w1c_val(aw1,o,q,h,2*dw+1));
    return;
  } j -= 6144;
  if(j < 64){ ws[OFF_AB1 + j] = ab1[j]; return; } j -= 64;
  if(j < 1024){ // W2H: [32 pp][4 q][8 dw]; aw2 is [32 out][64 in]
    int pp = j>>5, q = (j>>3)&3, dw = j&7;
    int o = 8*q + dw;
    wsu[OFF_W2H + j] = pack2h(aw2[o*64 + 2*pp], aw2[o*64 + 2*pp+1]);
    return;
  } j -= 1024;
  if(j < 32){ ws[OFF_AB2 + j] = ab2[j]; return; } j -= 32;
  if(j < 32){ ws[OFF_W3  + j] = aw3[j]; return; } j -= 32;
  if(j < 1){ ws[OFF_AB3] = ab3[0]; return; } j -= 1;
  if(j < 64){ ws[OFF_MB2 + j] = mb2[j]; return; } j -= 64;
  if(j < 32){ ws[OFF_MB3 + j] = mb3[j]; return; } j -= 32;
  if(j < 32){ ws[OFF_M4  + j] = m4[j];  return; } j -= 32;
  if(j < 1){ ws[OFF_MB4] = mb4[0]; return; } j -= 1;
  if(j < 2){ ws[7426 + j] = 0.f; return; } j -= 2;  // pad
  if(j < 1024){ // M3H: [4 q][8 ip][32 dw]; m3 is [32 out][64 in]
    int qq = j>>8, rr = j&255, ip = rr>>5, dw = rr&31;
    wsu[OFF_M3H + j] = pack2h(m3[dw*64 + 16*qq + 2*ip], m3[dw*64 + 16*qq + 2*ip+1]);
    return;
  } j -= 1024;
  if(j < 14336){ // W1F MFMA B-frags: lane holds col=l&15, k=(l>>4)*8+j8
    int frag = j>>2, jr = j&3;
    int lane = frag & 63, nt = frag >> 6;
    int n = nt/7, t = nt - 7*n;
    int o = 16*n + (lane&15);
    int k0 = t*32 + ((lane>>4)<<3) + 2*jr;
    wsu[OFF_W1F + j] = pack2h(m1k(m1,o,k0), m1k(m1,o,k0+1));
    return;
  } j -= 14336;
  if(j < 128){ ws[OFF_MB1 + j] = mb1[j]; return; } j -= 128;
  if(j < 4096){ // W2F MFMA B-frags; m2 is [64 out][128 in], k = natural H1 col
    int frag = j>>2, jr = j&3;
    int lane = frag & 63, nt = frag >> 6;
    int n2 = nt>>2, t2 = nt&3;
    int o = 16*n2 + (lane&15);
    int k0 = t2*32 + ((lane>>4)<<3) + 2*jr;
    wsu[OFF_W2F + j] = pack2h(m2[o*128 + k0], m2[o*128 + k0+1]);
    return;
  }
}

// DPP quad reduction: no LDS-pipe traffic
template<int CTL>
__device__ __forceinline__ float qp(float v){
  return __uint_as_float((unsigned)__builtin_amdgcn_update_dpp(
      0, (int)__float_as_uint(v), CTL, 0xF, 0xF, true));
}
__device__ __forceinline__ float bsum4(float v){
  v += qp<0xB1>(v);
  v += qp<0x4E>(v);
  return v;
}

// async global->LDS staging
__device__ __forceinline__ void ldst16(void* l, const void* g){
  __builtin_amdgcn_global_load_lds(
      (const __attribute__((address_space(1))) unsigned int*)(uintptr_t)g,
      (__attribute__((address_space(3))) unsigned int*)(uintptr_t)l, 16, 0, 0);
}
__device__ __forceinline__ void ldst4(void* l, const void* g){
  __builtin_amdgcn_global_load_lds(
      (const __attribute__((address_space(1))) unsigned int*)(uintptr_t)g,
      (__attribute__((address_space(3))) unsigned int*)(uintptr_t)l, 4, 0, 0);
}

// gather one 88-feature quad-slice as 11 packed f16 pairs
__device__ __forceinline__ void gather_h(const float2* __restrict__ itemp,
                                         const float2* __restrict__ kindp,
                                         int item_idx, const int* __restrict__ kidx,
                                         int q, v2h* f){
  float2 v = itemp[item_idx*4 + q];
  f[0] = pkh(v.x, v.y);
  #pragma unroll
  for(int r=0;r<KIND_LEN;r++){
    int ki = kidx[r];
    float2 w = kindp[ki*4 + q];
    float mx = ki ? w.x : 0.f, my = ki ? w.y : 0.f;
    f[1+r] = pkh(mx, my);
  }
}

// one history pass over NS steps (identical math to R9)
template<int NS>
__device__ __forceinline__ void hist_pass(int b, int s0, int q, int wid,
    const float2* __restrict__ item_emb, const float2* __restrict__ kind_emb,
    const int* __restrict__ his_id, const int* __restrict__ his_kind,
    const float* ls, const float4* ls4, const unsigned* tpu, v2f* poolv){
  v2h i1h[NS][11];
  #pragma unroll
  for(int t=0;t<NS;t++)
    gather_h(item_emb, kind_emb, his_id[b*HIS_LEN + s0 + t],
             his_kind + (b*HIS_LEN + s0 + t)*KIND_LEN, q, i1h[t]);
  float h2s[NS][8];
  #pragma unroll
  for(int t=0;t<NS;t++)
    #pragma unroll
    for(int k=0;k<8;k++) h2s[t][k] = 0.f;

  #pragma unroll 1
  for(int p=0;p<32;p++){
    const uint4* wr0 = (const uint4*)(ls4 + ((2*p  )*4+q)*3);
    const uint4* wr1 = (const uint4*)(ls4 + ((2*p+1)*4+q)*3);
    uint4 r0=wr0[0], r1=wr0[1], r2=wr0[2];
    uint4 s0v=wr1[0], s1v=wr1[1], s2v=wr1[2];
    unsigned w0[12] = {r0.x,r0.y,r0.z,r0.w, r1.x,r1.y,r1.z,r1.w, r2.x,r2.y,r2.z,r2.w};
    unsigned w1[12] = {s0v.x,s0v.y,s0v.z,s0v.w, s1v.x,s1v.y,s1v.z,s1v.w, s2v.x,s2v.y,s2v.z,s2v.w};
    v2h t2 = C2H(tpu[p*SB + wid]);
    v2h hpv[NS];
    #pragma unroll
    for(int t=0;t<NS;t++){
      float aA=0.f, aB=0.f, cA=0.f, cB=0.f;
      #pragma unroll
      for(int u=0;u<11;u++){
        if(u&1){ aB = FD2(C2H(w0[u]), i1h[t][u], aB); cB = FD2(C2H(w1[u]), i1h[t][u], cB); }
        else   { aA = FD2(C2H(w0[u]), i1h[t][u], aA); cA = FD2(C2H(w1[u]), i1h[t][u], cA); }
      }
      float h0 = fmaxf(bsum4(aA+aB) + (float)t2.x, 0.f);
      float h1 = fmaxf(bsum4(cA+cB) + (float)t2.y, 0.f);
      hpv[t] = pkh(h0, h1);
    }
    uint4 wa = *(const uint4*)(ls4 + W2HF4 + (p*4+q)*2);
    uint4 wb = *(const uint4*)(ls4 + W2HF4 + (p*4+q)*2 + 1);
    unsigned w2d[8] = {wa.x,wa.y,wa.z,wa.w, wb.x,wb.y,wb.z,wb.w};
    #pragma unroll
    for(int t=0;t<NS;t++)
      #pragma unroll
      for(int k=0;k<8;k++) h2s[t][k] = FD2(C2H(w2d[k]), hpv[t], h2s[t][k]);
  }
  #pragma unroll
  for(int t=0;t<NS;t++){
    float scp = 0.f;
    #pragma unroll
    for(int j=0;j<8;j++){
      float hx = fmaxf(h2s[t][j] + ls[PFF+1088+8*q+j], 0.f);
      scp += ls[PFF+1120+8*q+j]*hx;
    }
    float sc = bsum4(scp) + ls[PFF+1152];
    #pragma unroll
    for(int j=0;j<11;j++){
      float sx = (float)i1h[t][j].x, sy = (float)i1h[t][j].y;
      poolv[j] = __builtin_elementwise_fma(mk2(sx*sc, sy*sc), mk2(sx, sy), poolv[j]);
    }
  }
}

// 256 threads; 64 samples/block; history quad-split; MLP via MFMA 16x16x32 f16.
__global__ void __launch_bounds__(NTH, 4)
din_main(const int* __restrict__ userid, const int* __restrict__ itemid,
         const int* __restrict__ age,    const int* __restrict__ gen,
         const int* __restrict__ occ,    const int* __restrict__ item_kind,
         const int* __restrict__ his_id, const int* __restrict__ his_kind,
         const float2* __restrict__ user_emb, const float2* __restrict__ item_emb,
         const float2* __restrict__ age_emb,  const float2* __restrict__ gen_emb,
         const float2* __restrict__ occ_emb,  const float2* __restrict__ kind_emb,
         const float* __restrict__ ws, float* __restrict__ out){
  const int tid  = threadIdx.x;
  const int q    = tid & 3;
  const int sl   = (tid & 63) >> 2;
  const int wv   = __builtin_amdgcn_readfirstlane(tid >> 6);
  const int wid  = wv*16 + sl;                 // sample-in-block 0..63
  const int b    = blockIdx.x*SB + wid;
  const int l    = tid & 63;                   // lane
  const int sA   = wv*16 + (l&15);             // MFMA A-row (sample)
  const int kb   = l >> 4;                     // MFMA K-block 0..3

  __shared__ __align__(16) float ls[LDSF];
  float4* ls4 = (float4*)ls;
  const float* wsc = ws;
  const float4* ws4 = (const float4*)ws;
  const uint4* wsu4 = (const uint4*)ws;
  unsigned* tpu = (unsigned*)(ls + TPF);

  // ---- initial async staging: PF (1282 f) + MB1 (128 f) + W1C16 (1536 f4) ----
  #pragma unroll
  for(int k=0;k<5;k++){ int j = k*NTH + tid; ldst4(ls + PFF + j, wsc + OFF_AB1 + j); }
  { int j = 5*NTH + tid;
    if(j < 1282) ldst4(ls + PFF + j, wsc + OFF_AB1 + j); }
  if(tid < 128) ldst4(ls + MB1F + tid, wsc + OFF_MB1 + tid);
  #pragma unroll
  for(int k=0;k<6;k++){ int j = k*NTH + tid; ldst16(ls4 + j, ws4 + j); }

  // ---- i2 slice as packed f16 (overlaps staging latency) ----
  v2h i2h[11];
  gather_h(item_emb, kind_emb, itemid[b], item_kind + b*KIND_LEN, q, i2h);

  __syncthreads();   // staging drained

  // ---- phase A: t2+ab1 -> paired f16 tp (h=1 weights, f4 [768,1536)) ----
  #pragma unroll 1
  for(int p=0;p<32;p++){
    const uint4* wr0 = (const uint4*)(ls4 + 768 + ((2*p  )*4+q)*3);
    const uint4* wr1 = (const uint4*)(ls4 + 768 + ((2*p+1)*4+q)*3);
    uint4 r0=wr0[0], r1=wr0[1], r2=wr0[2];
    uint4 s0v=wr1[0], s1v=wr1[1], s2v=wr1[2];
    unsigned w0[12] = {r0.x,r0.y,r0.z,r0.w, r1.x,r1.y,r1.z,r1.w, r2.x,r2.y,r2.z,r2.w};
    unsigned w1[12] = {s0v.x,s0v.y,s0v.z,s0v.w, s1v.x,s1v.y,s1v.z,s1v.w, s2v.x,s2v.y,s2v.z,s2v.w};
    float aA=0.f, aB=0.f, cA=0.f, cB=0.f;
    #pragma unroll
    for(int u=0;u<11;u++){
      if(u&1){ aB = FD2(C2H(w0[u]), i2h[u], aB); cB = FD2(C2H(w1[u]), i2h[u], cB); }
      else   { aA = FD2(C2H(w0[u]), i2h[u], aA); cA = FD2(C2H(w1[u]), i2h[u], cA); }
    }
    float sA2 = bsum4(aA+aB), sB2 = bsum4(cA+cB);
    if(q==0){
      float2 bb = ((const float2*)(ls+PFF))[p];
      tpu[p*SB + wid] = __builtin_bit_cast(unsigned, pkh(sA2+bb.x, sB2+bb.y));
    }
  }
  __syncthreads();   // tp visible to quad

  // ---- history: 3 passes (2+2+1 steps), no barriers ----
  v2f poolv[11];
  #pragma unroll
  for(int d=0;d<11;d++) poolv[d]=mk2(0.f,0.f);
  hist_pass<2>(b, 0, q, wid, item_emb, kind_emb, his_id, his_kind, ls, ls4, tpu, poolv);
  hist_pass<2>(b, 2, q, wid, item_emb, kind_emb, his_id, his_kind, ls, ls4, tpu, poolv);
  hist_pass<1>(b, 4, q, wid, item_emb, kind_emb, his_id, his_kind, ls, ls4, tpu, poolv);

  // ---- feature vector fe[26] (extras | i2 | pool), k-order [q][56] ----
  gather_h(item_emb, kind_emb, itemid[b], item_kind + b*KIND_LEN, q, i2h);
  v2h fe[26];
  {
    const float2* ep = (q==0)? user_emb : (q==1)? age_emb : (q==2)? gen_emb : occ_emb;
    int ei = (q==0)? userid[b] : (q==1)? age[b] : (q==2)? gen[b] : occ[b];
    #pragma unroll
    for(int k=0;k<4;k++){ float2 v = ep[ei*4+k]; fe[k] = pkh(v.x, v.y); }
  }
  #pragma unroll
  for(int j=0;j<11;j++) fe[4+j]  = i2h[j];
  #pragma unroll
  for(int j=0;j<11;j++) fe[15+j] = pkh(poolv[j].x, poolv[j].y);

  __syncthreads();   // B0: all history reads of W1C16/tp done

  // ---- X materialization: row wid, dw [q*28, q*28+28) of 116-dw row (29 f4) ----
  {
    unsigned xd[28];
    #pragma unroll
    for(int u=0;u<26;u++) xd[u] = __builtin_bit_cast(unsigned, fe[u]);
    xd[26] = 0; xd[27] = 0;
    uint4* xp = (uint4*)(ls4 + wid*29 + q*7);
    #pragma unroll
    for(int ct=0; ct<7; ct++){
      uint4 t; t.x=xd[4*ct]; t.y=xd[4*ct+1]; t.z=xd[4*ct+2]; t.w=xd[4*ct+3];
      xp[ct] = t;
    }
  }
  __syncthreads();   // B1: X complete

  // ---- A-fragments for MLP1 (held in registers across all N-tiles) ----
  uint4 af[7];
  #pragma unroll
  for(int t=0;t<7;t++) af[t] = *(const uint4*)(ls4 + sA*29 + t*4 + kb);

  // stage tail M3H weights (region f4 [1856,2118), disjoint from X/H1/H2)
  ldst16(ls4 + M3HL + (tid>>6)*66 + (tid&63), ws4 + M3H4 + tid);

  __syncthreads();   // B2: A-frags loaded; X region free for H1/H2

  // ---- MLP1: H1[64x128] = X·W1 + mb1, ReLU; B-frags direct from global ----
  v4f acc1[8];
  #pragma unroll
  for(int n=0;n<8;n++){
    float bb = ls[MB1F + n*16 + (l&15)];
    v4f c = {bb, bb, bb, bb};
    #pragma unroll
    for(int t=0;t<7;t++){
      uint4 bw = wsu4[W1F4 + (n*7+t)*64 + l];
      c = __builtin_amdgcn_mfma_f32_16x16x32_f16(C8H(af[t]), C8H(bw), c, 0, 0, 0);
    }
    acc1[n] = c;
  }
  {
    _Float16* h1p = (_Float16*)ls;   // row stride 136 f16 (17 f4)
    #pragma unroll
    for(int n=0;n<8;n++)
      #pragma unroll
      for(int i=0;i<4;i++)
        h1p[(wv*16 + kb*4 + i)*136 + 16*n + (l&15)] =
            (_Float16)fmaxf(acc1[n][i], 0.f);
  }
  __syncthreads();   // B3: H1 ready

  // ---- MLP2: H2[64x64] = H1·W2 + mb2, ReLU; A from H1 LDS, B from global ----
  v4f acc2[4];
  #pragma unroll
  for(int n2=0;n2<4;n2++){
    float bb = ls[PFF+1153 + n2*16 + (l&15)];
    v4f c = {bb, bb, bb, bb};
    acc2[n2] = c;
  }
  #pragma unroll
  for(int t2=0;t2<4;t2++){
    uint4 aw = *(const uint4*)(ls4 + sA*17 + t2*4 + kb);
    #pragma unroll
    for(int n2=0;n2<4;n2++){
      uint4 bw = wsu4[W2F4 + (n2*4+t2)*64 + l];
      acc2[n2] = __builtin_amdgcn_mfma_f32_16x16x32_f16(C8H(aw), C8H(bw), acc2[n2], 0, 0, 0);
    }
  }
  {
    _Float16* h2p = (_Float16*)(ls4 + H2F4);   // row stride 72 f16 (9 f4)
    #pragma unroll
    for(int n2=0;n2<4;n2++)
      #pragma unroll
      for(int i=0;i<4;i++)
        h2p[(wv*16 + kb*4 + i)*72 + 16*n2 + (l&15)] =
            (_Float16)fmaxf(acc2[n2][i], 0.f);
  }
  __syncthreads();   // B4: H2 + M3H ready

  // ---- tail: layers 3+4 (per-sample quad, i-paired fdot2) ----
  v2h hp3[8];
  {
    const uint4* hr = (const uint4*)(ls4 + H2F4 + wid*9 + 2*q);
    uint4 d0 = hr[0], d1 = hr[1];
    hp3[0]=C2H(d0.x); hp3[1]=C2H(d0.y); hp3[2]=C2H(d0.z); hp3[3]=C2H(d0.w);
    hp3[4]=C2H(d1.x); hp3[5]=C2H(d1.y); hp3[6]=C2H(d1.z); hp3[7]=C2H(d1.w);
  }
  float x = ls[PFF+1281];
  #pragma unroll
  for(int g=0;g<4;g++){
    float a[8];
    #pragma unroll
    for(int j=0;j<8;j++) a[j]=0.f;
    #pragma unroll
    for(int ip=0;ip<8;ip++){
      const uint4* w3p = (const uint4*)(ls4 + M3HL + q*66 + ip*8 + 2*g);
      uint4 b0=w3p[0], b1=w3p[1];
      a[0]=FD2(C2H(b0.x),hp3[ip],a[0]); a[1]=FD2(C2H(b0.y),hp3[ip],a[1]);
      a[2]=FD2(C2H(b0.z),hp3[ip],a[2]); a[3]=FD2(C2H(b0.w),hp3[ip],a[3]);
      a[4]=FD2(C2H(b1.x),hp3[ip],a[4]); a[5]=FD2(C2H(b1.y),hp3[ip],a[5]);
      a[6]=FD2(C2H(b1.z),hp3[ip],a[6]); a[7]=FD2(C2H(b1.w),hp3[ip],a[7]);
    }
    #pragma unroll
    for(int j=0;j<8;j++) a[j] = bsum4(a[j]);
    #pragma unroll
    for(int j=0;j<8;j++)
      x += ls[PFF+1249+8*g+j] * fmaxf(a[j] + ls[PFF+1217+8*g+j], 0.f);
  }

  if(q==0) out[b] = 1.0f/(1.0f + __expf(-x));
}

extern "C" void kernel_launch(void* const* d_in, const int* in_sizes, int n_in,
                              void* d_out, int out_size, void* d_ws, size_t ws_size,
                              hipStream_t stream){
  const int* userid    = (const int*)d_in[0];
  const int* itemid    = (const int*)d_in[1];
  const int* age       = (const int*)d_in[2];
  const int* gen       = (const int*)d_in[3];
  const int* occ       = (const int*)d_in[4];
  const int* item_kind = (const int*)d_in[5];
  const int* his_id    = (const int*)d_in[6];
  const int* his_kind  = (const int*)d_in[7];
  const float2* user_emb = (const float2*)d_in[8];
  const float2* item_emb = (const float2*)d_in[9];
  const float2* age_emb  = (const float2*)d_in[10];
  const float2* gen_emb  = (const float2*)d_in[11];
  const float2* occ_emb  = (const float2*)d_in[12];
  const float2* kind_emb = (const float2*)d_in[13];
  float* ws = (float*)d_ws;

  din_prep<<<(PREP_N+255)/256, 256, 0, stream>>>(
      (fp)d_in[14], (fp)d_in[15], (fp)d_in[16], (fp)d_in[17], (fp)d_in[18], (fp)d_in[19],
      (fp)d_in[20], (fp)d_in[21], (fp)d_in[22], (fp)d_in[23], (fp)d_in[24], (fp)d_in[25],
      (fp)d_in[26], (fp)d_in[27], ws);

  din_main<<<BATCH/SB, NTH, 0, stream>>>(
      userid, itemid, age, gen, occ, item_kind, his_id, his_kind,
      user_emb, item_emb, age_emb, gen_emb, occ_emb, kind_emb,
      ws, (float*)d_out);
}

// Round 11
// 238.090 us; speedup vs baseline: 3.1447x; 1.0173x over previous
//
#include <hip/hip_runtime.h>
#include <cstdint>
#include <math.h>

#define BATCH    65536
#define HIS_LEN  5
#define KIND_LEN 10
#define SB       64    // samples per block
#define NTH      256   // threads per block (4 waves); 4 threads per sample

typedef float    v2f __attribute__((ext_vector_type(2)));
typedef float    v4f __attribute__((ext_vector_type(4)));
typedef _Float16 v2h __attribute__((ext_vector_type(2)));
typedef _Float16 v8h __attribute__((ext_vector_type(8)));
__device__ __forceinline__ v2f mk2(float a, float b){ v2f r; r.x=a; r.y=b; return r; }
#define C2H(u)  __builtin_bit_cast(v2h,(unsigned)(u))
#define C8H(u4) __builtin_bit_cast(v8h,(u4))

#if __has_builtin(__builtin_amdgcn_fdot2)
__device__ __forceinline__ float FD2(v2h a, v2h b, float c){
  return __builtin_amdgcn_fdot2(a, b, c, false);
}
#else
__device__ __forceinline__ float FD2(v2h a, v2h b, float c){
  return c + (float)a.x*(float)b.x + (float)a.y*(float)b.y;
}
#endif

__device__ __forceinline__ unsigned short f2h(float f){
  return __builtin_bit_cast(unsigned short, (_Float16)f);
}
__device__ __forceinline__ unsigned pack2h(float a, float b){
  return (unsigned)f2h(a) | ((unsigned)f2h(b) << 16);
}
__device__ __forceinline__ v2h pkh(float a, float b){
  return __builtin_bit_cast(v2h, __builtin_amdgcn_cvt_pkrtz(a, b));
}

// ---- ws layout (dword offsets) ----
#define OFF_HW1F 0      // 6144: hist W1 B-frags [4n][6t][64 lane][4dw], K=192=[i1|i2]
#define OFF_AW2F 6144   // 1024: act W2 B-frags [2n2][2t2][64][4]
#define OFF_PF   7168   // 258: AB1 64|AB2 32|W3 32|AB3 1|MB2 64|MB3 32|M4 32|MB4 1
#define OFF_M3H  7428   // 1024: tail M3 f16 pairs [4q][8ip][32dw]
#define OFF_MW1F 8452   // 14336: MLP W1 B-frags [8n][7t][64][4]
#define OFF_MB1  22788  // 128
#define OFF_MW2F 22916  // 4096: MLP W2 B-frags [4n2][4t2][64][4]
#define PREP_N   27012
// f4 indices into ws
#define AW2F4 1536
#define M3H4  1857
#define MW1F4 2113
#define MW2F4 5729

// ---- LDS layout (f4 units unless noted) ----
//  X2  [0,832):     i2 features [64 rows][13 f4] (96 f16/row, q-major)
//  X1  [832,1664):  i1 features per step, same shape
//  H1  [1664,2240): hist hidden f16 [64][9 f4] (64 f16 + pad)
//  H2  [2240,2816): act hidden f32 [64][9 f4] (32 f32 + pad)
//  M3H [2816,3078): tail weights (skewed, q*66)
//  PF  f[12312,12570) ; MB1 f[12572,12700)
//  MLP phase reuses [0,1856): X-MLP [64][29]; then H1-MLP [0,1088) s17, H2-MLP [1088,1664) s9
#define X2B   0
#define X1B   832
#define H1B   1664
#define H2B   2240
#define M3HL  2816
#define LAB1  12312
#define LAB2  12376
#define LW3   12408
#define LAB3  12440
#define LMB2  12441
#define LMB3  12505
#define LM4   12537
#define LMB4  12569
#define MB1F  12572
#define LDSF  12700

typedef const float* fp;

__device__ __forceinline__ float m1s_val(fp m1, int o, int q, int t){
  if(t >= 52) return 0.f;
  int src;
  if(t<8){ int E = (q==0)?0:(8+8*q); src = E + t; }
  else if(t<30){ int d=t-8; int idx = 8*(d>>1)+2*q+(d&1);
                 src = (idx<8) ? (8+idx) : (32+idx); }
  else { int d=t-30; int idx = 8*(d>>1)+2*q+(d&1); src = 120+idx; }
  return m1[o*208 + src];
}
__device__ __forceinline__ float m1k(fp m1, int o, int k){   // k in [0,224)
  return m1s_val(m1, o, k/56, k%56);
}
__device__ __forceinline__ float w1c_val(fp aw1, int o, int q, int h, int d){
  if(d >= 22) return 0.f;
  int idx = 8*(d>>1) + 2*q + (d&1);
  return h ? (aw1[o*264+176+idx] - aw1[o*264+88+idx])
           : (aw1[o*264+idx]     + aw1[o*264+88+idx]);
}
// hist combined-W1 element: k in [0,192): k<96 -> i1 (h0), else i2 (h1)
__device__ __forceinline__ float hw1v(fp aw1, int o, int k){
  int h = (k >= 96) ? 1 : 0;
  int kk = k - 96*h;
  int q = kk/24, d = kk%24;
  return (d<22) ? w1c_val(aw1,o,q,h,d) : 0.f;
}

__global__ void din_prep(fp aw1, fp ab1, fp aw2, fp ab2, fp aw3, fp ab3,
                         fp m1,  fp mb1, fp m2,  fp mb2, fp m3,  fp mb3,
                         fp m4,  fp mb4, float* __restrict__ ws){
  int j = blockIdx.x*blockDim.x + threadIdx.x;
  unsigned* wsu = (unsigned*)ws;
  if(j < 6144){ // HW1F: [4n][6t][64][4]
    int frag = j>>2, jr = j&3;
    int lane = frag & 63, nt = frag >> 6;      // nt in [0,24)
    int n = nt/6, t = nt%6;
    int o = 16*n + (lane&15);
    int k0 = t*32 + ((lane>>4)<<3) + 2*jr;
    wsu[OFF_HW1F + j] = pack2h(hw1v(aw1,o,k0), hw1v(aw1,o,k0+1));
    return;
  } j -= 6144;
  if(j < 1024){ // AW2F: [2n2][2t2][64][4]; aw2 is [32 out][64 in]
    int frag = j>>2, jr = j&3;
    int lane = frag & 63, nt = frag >> 6;      // nt in [0,4)
    int n2 = nt>>1, t2 = nt&1;
    int o = 16*n2 + (lane&15);
    int k0 = t2*32 + ((lane>>4)<<3) + 2*jr;
    wsu[OFF_AW2F + j] = pack2h(aw2[o*64 + k0], aw2[o*64 + k0+1]);
    return;
  } j -= 1024;
  if(j < 258){ // PF
    float v;
    if(j < 64)       v = ab1[j];
    else if(j < 96)  v = ab2[j-64];
    else if(j < 128) v = aw3[j-96];
    else if(j < 129) v = ab3[0];
    else if(j < 193) v = mb2[j-129];
    else if(j < 225) v = mb3[j-193];
    else if(j < 257) v = m4[j-225];
    else             v = mb4[0];
    ws[OFF_PF + j] = v; return;
  } j -= 258;
  if(j < 2){ ws[OFF_PF+258+j] = 0.f; return; } j -= 2;  // pad to 7428
  if(j < 1024){ // M3H: [4q][8ip][32dw]
    int qq = j>>8, rr = j&255, ip = rr>>5, dw = rr&31;
    wsu[OFF_M3H + j] = pack2h(m3[dw*64 + 16*qq + 2*ip], m3[dw*64 + 16*qq + 2*ip+1]);
    return;
  } j -= 1024;
  if(j < 14336){ // MW1F: [8n][7t][64][4], k-order [q][56]
    int frag = j>>2, jr = j&3;
    int lane = frag & 63, nt = frag >> 6;
    int n = nt/7, t = nt - 7*n;
    int o = 16*n + (lane&15);
    int k0 = t*32 + ((lane>>4)<<3) + 2*jr;
    wsu[OFF_MW1F + j] = pack2h(m1k(m1,o,k0), m1k(m1,o,k0+1));
    return;
  } j -= 14336;
  if(j < 128){ ws[OFF_MB1 + j] = mb1[j]; return; } j -= 128;
  if(j < 4096){ // MW2F: [4n2][4t2][64][4]
    int frag = j>>2, jr = j&3;
    int lane = frag & 63, nt = frag >> 6;
    int n2 = nt>>2, t2 = nt&3;
    int o = 16*n2 + (lane&15);
    int k0 = t2*32 + ((lane>>4)<<3) + 2*jr;
    wsu[OFF_MW2F + j] = pack2h(m2[o*128 + k0], m2[o*128 + k0+1]);
    return;
  }
}

// DPP quad reduction
template<int CTL>
__device__ __forceinline__ float qp(float v){
  return __uint_as_float((unsigned)__builtin_amdgcn_update_dpp(
      0, (int)__float_as_uint(v), CTL, 0xF, 0xF, true));
}
__device__ __forceinline__ float bsum4(float v){
  v += qp<0xB1>(v);
  v += qp<0x4E>(v);
  return v;
}

__device__ __forceinline__ void ldst16(void* l, const void* g){
  __builtin_amdgcn_global_load_lds(
      (const __attribute__((address_space(1))) unsigned int*)(uintptr_t)g,
      (__attribute__((address_space(3))) unsigned int*)(uintptr_t)l, 16, 0, 0);
}
__device__ __forceinline__ void ldst4(void* l, const void* g){
  __builtin_amdgcn_global_load_lds(
      (const __attribute__((address_space(1))) unsigned int*)(uintptr_t)g,
      (__attribute__((address_space(3))) unsigned int*)(uintptr_t)l, 4, 0, 0);
}

// gather one 88-feature quad-slice as 11 packed f16 pairs
__device__ __forceinline__ void gather_h(const float2* __restrict__ itemp,
                                         const float2* __restrict__ kindp,
                                         int item_idx, const int* __restrict__ kidx,
                                         int q, v2h* f){
  float2 v = itemp[item_idx*4 + q];
  f[0] = pkh(v.x, v.y);
  #pragma unroll
  for(int r=0;r<KIND_LEN;r++){
    int ki = kidx[r];
    float2 w = kindp[ki*4 + q];
    float mx = ki ? w.x : 0.f, my = ki ? w.y : 0.f;
    f[1+r] = pkh(mx, my);
  }
}

// write one feature row slice into X region (row stride 13 f4; lane q owns 3 f4)
__device__ __forceinline__ void write_X(float4* ls4, int base, int wid, int q,
                                        const v2h* f){
  unsigned xd[12];
  #pragma unroll
  for(int r=0;r<11;r++) xd[r] = __builtin_bit_cast(unsigned, f[r]);
  xd[11] = 0;
  uint4* xp = (uint4*)(ls4 + base + wid*13 + 3*q);
  #pragma unroll
  for(int c=0;c<3;c++){
    uint4 t; t.x=xd[4*c]; t.y=xd[4*c+1]; t.z=xd[4*c+2]; t.w=xd[4*c+3];
    xp[c] = t;
  }
}

// 256 threads; 64 samples/block; history AND MLP via MFMA 16x16x32 f16.
__global__ void __launch_bounds__(NTH, 3)
din_main(const int* __restrict__ userid, const int* __restrict__ itemid,
         const int* __restrict__ age,    const int* __restrict__ gen,
         const int* __restrict__ occ,    const int* __restrict__ item_kind,
         const int* __restrict__ his_id, const int* __restrict__ his_kind,
         const float2* __restrict__ user_emb, const float2* __restrict__ item_emb,
         const float2* __restrict__ age_emb,  const float2* __restrict__ gen_emb,
         const float2* __restrict__ occ_emb,  const float2* __restrict__ kind_emb,
         const float* __restrict__ ws, float* __restrict__ out){
  const int tid  = threadIdx.x;
  const int q    = tid & 3;
  const int sl   = (tid & 63) >> 2;
  const int wv   = __builtin_amdgcn_readfirstlane(tid >> 6);
  const int wid  = wv*16 + sl;                 // sample-in-block 0..63
  const int b    = blockIdx.x*SB + wid;
  const int l    = tid & 63;
  const int sr   = wv*16 + (l&15);             // MFMA A-row (sample)
  const int kb   = l >> 4;                     // MFMA K-chunk 0..3

  __shared__ __align__(16) float ls[LDSF];
  float4* ls4 = (float4*)ls;
  const uint4* lsu4 = (const uint4*)ls;
  const float* wsc = ws;
  const float4* ws4 = (const float4*)ws;
  const uint4* wsu4 = (const uint4*)ws;

  // ---- initial async staging: PF(258) + MB1(128) + M3H(skewed) ----
  ldst4(ls + LAB1 + tid, wsc + OFF_PF + tid);
  if(tid < 2)   ldst4(ls + LAB1 + 256 + tid, wsc + OFF_PF + 256 + tid);
  if(tid < 128) ldst4(ls + MB1F + tid, wsc + OFF_MB1 + tid);
  ldst16(ls4 + M3HL + (tid>>6)*66 + (tid&63), ws4 + M3H4 + tid);

  // ---- gather i2 -> X2 (persistent K-tiles 3..5) ----
  {
    v2h i2t[11];
    gather_h(item_emb, kind_emb, itemid[b], item_kind + b*KIND_LEN, q, i2t);
    write_X(ls4, X2B, wid, q, i2t);
  }
  // ---- gather step-0 i1 ----
  v2h i1c[11], i1n[11];
  gather_h(item_emb, kind_emb, his_id[b*HIS_LEN], his_kind + b*HIS_LEN*KIND_LEN,
           q, i1c);

  v2f poolv[11];
  #pragma unroll
  for(int d=0;d<11;d++) poolv[d]=mk2(0.f,0.f);
  v2h i2h[11];
  float2 exr[4];

  __syncthreads();   // staging + X2 drained

  // ---- history: 5 steps, MFMA act-unit ----
  #pragma unroll 1
  for(int s=0;s<5;s++){
    write_X(ls4, X1B, wid, q, i1c);
    __syncthreads();                       // BAR1: X1 ready
    if(s < 4){
      gather_h(item_emb, kind_emb, his_id[b*HIS_LEN+s+1],
               his_kind + (b*HIS_LEN+s+1)*KIND_LEN, q, i1n);
    } else {
      // prefetch MLP inputs under the last step's MFMAs
      gather_h(item_emb, kind_emb, itemid[b], item_kind + b*KIND_LEN, q, i2h);
      const float2* ep = (q==0)? user_emb : (q==1)? age_emb : (q==2)? gen_emb : occ_emb;
      int ei = (q==0)? userid[b] : (q==1)? age[b] : (q==2)? gen[b] : occ[b];
      #pragma unroll
      for(int k=0;k<4;k++) exr[k] = ep[ei*4+k];
    }
    // MFMA1: hidden[64 x 64] = [X1|X2]·HW1 + ab1, relu -> H1 (f16)
    {
      uint4 a1[6];
      #pragma unroll
      for(int t=0;t<3;t++) a1[t]   = lsu4[X2B*0 + X1B + sr*13 + 4*t + kb];
      #pragma unroll
      for(int t=0;t<3;t++) a1[3+t] = lsu4[X2B + sr*13 + 4*t + kb];
      _Float16* h1p = (_Float16*)(ls4 + H1B);
      #pragma unroll
      for(int n=0;n<4;n++){
        float bb = ls[LAB1 + 16*n + (l&15)];
        v4f c = {bb,bb,bb,bb};
        #pragma unroll
        for(int t=0;t<6;t++){
          uint4 bw = wsu4[(n*6+t)*64 + l];
          c = __builtin_amdgcn_mfma_f32_16x16x32_f16(C8H(a1[t]), C8H(bw), c, 0, 0, 0);
        }
        #pragma unroll
        for(int i=0;i<4;i++)
          h1p[(16*wv + 4*kb + i)*72 + 16*n + (l&15)] = (_Float16)fmaxf(c[i],0.f);
      }
    }
    __syncthreads();                       // BAR2: H1 ready
    // MFMA2: h2[64 x 32] = H1·AW2 + ab2, relu -> H2 (f32)
    {
      uint4 a2[2];
      #pragma unroll
      for(int t=0;t<2;t++) a2[t] = lsu4[H1B + sr*9 + 4*t + kb];
      float* h2p = (float*)(ls4 + H2B);
      #pragma unroll
      for(int n2=0;n2<2;n2++){
        float bb = ls[LAB2 + 16*n2 + (l&15)];
        v4f c = {bb,bb,bb,bb};
        #pragma unroll
        for(int t=0;t<2;t++){
          uint4 bw = wsu4[AW2F4 + (n2*2+t)*64 + l];
          c = __builtin_amdgcn_mfma_f32_16x16x32_f16(C8H(a2[t]), C8H(bw), c, 0, 0, 0);
        }
        #pragma unroll
        for(int i=0;i<4;i++)
          h2p[(16*wv + 4*kb + i)*36 + 16*n2 + (l&15)] = fmaxf(c[i],0.f);
      }
    }
    __syncthreads();                       // BAR3: H2 ready
    // act tail: sc = w3·H2 + ab3 ; pool += sc * i1^2
    {
      const float4* hr = (const float4*)(ls4 + H2B + wid*9 + 2*q);
      float4 h0 = hr[0], h1v = hr[1];
      float scp = h0.x*ls[LW3+8*q]   + h0.y*ls[LW3+8*q+1]
                + h0.z*ls[LW3+8*q+2] + h0.w*ls[LW3+8*q+3]
                + h1v.x*ls[LW3+8*q+4] + h1v.y*ls[LW3+8*q+5]
                + h1v.z*ls[LW3+8*q+6] + h1v.w*ls[LW3+8*q+7];
      float sc = bsum4(scp) + ls[LAB3];
      #pragma unroll
      for(int j=0;j<11;j++){
        float sx = (float)i1c[j].x, sy = (float)i1c[j].y;
        poolv[j] = __builtin_elementwise_fma(mk2(sx*sc, sy*sc), mk2(sx, sy), poolv[j]);
      }
    }
    #pragma unroll
    for(int j=0;j<11;j++) i1c[j] = i1n[j];
  }

  // ---- MLP phase (R10 structure): fe -> X-MLP -> MFMA1 -> MFMA2 -> tail ----
  v2h fe[26];
  #pragma unroll
  for(int k=0;k<4;k++) fe[k] = pkh(exr[k].x, exr[k].y);
  #pragma unroll
  for(int j=0;j<11;j++) fe[4+j]  = i2h[j];
  #pragma unroll
  for(int j=0;j<11;j++) fe[15+j] = pkh(poolv[j].x, poolv[j].y);

  // X-MLP write: [64][29 f4], k-order [q][56] (26 dw data + 2 pad per q)
  {
    unsigned xd[28];
    #pragma unroll
    for(int u=0;u<26;u++) xd[u] = __builtin_bit_cast(unsigned, fe[u]);
    xd[26] = 0; xd[27] = 0;
    uint4* xp = (uint4*)(ls4 + wid*29 + q*7);
    #pragma unroll
    for(int ct=0; ct<7; ct++){
      uint4 t; t.x=xd[4*ct]; t.y=xd[4*ct+1]; t.z=xd[4*ct+2]; t.w=xd[4*ct+3];
      xp[ct] = t;
    }
  }
  __syncthreads();   // B1: X-MLP complete (also: all history reads done)

  uint4 af[7];
  #pragma unroll
  for(int t=0;t<7;t++) af[t] = lsu4[sr*29 + t*4 + kb];
  __syncthreads();   // B2: A-frags loaded; [0,1856) free for H1/H2-MLP

  // MLP1: H1[64x128] = X·W1 + mb1, ReLU
  v4f acc1[8];
  #pragma unroll
  for(int n=0;n<8;n++){
    float bb = ls[MB1F + n*16 + (l&15)];
    v4f c = {bb, bb, bb, bb};
    #pragma unroll
    for(int t=0;t<7;t++){
      uint4 bw = wsu4[MW1F4 + (n*7+t)*64 + l];
      c = __builtin_amdgcn_mfma_f32_16x16x32_f16(C8H(af[t]), C8H(bw), c, 0, 0, 0);
    }
    acc1[n] = c;
  }
  {
    _Float16* h1p = (_Float16*)ls;   // row stride 136 f16 (17 f4)
    #pragma unroll
    for(int n=0;n<8;n++)
      #pragma unroll
      for(int i=0;i<4;i++)
        h1p[(16*wv + 4*kb + i)*136 + 16*n + (l&15)] =
            (_Float16)fmaxf(acc1[n][i], 0.f);
  }
  __syncthreads();   // B3: H1-MLP ready

  // MLP2: H2[64x64] = H1·W2 + mb2, ReLU
  v4f acc2[4];
  #pragma unroll
  for(int n2=0;n2<4;n2++){
    float bb = ls[LMB2 + n2*16 + (l&15)];
    v4f c = {bb, bb, bb, bb};
    acc2[n2] = c;
  }
  #pragma unroll
  for(int t2=0;t2<4;t2++){
    uint4 aw = lsu4[sr*17 + t2*4 + kb];
    #pragma unroll
    for(int n2=0;n2<4;n2++){
      uint4 bw = wsu4[MW2F4 + (n2*4+t2)*64 + l];
      acc2[n2] = __builtin_amdgcn_mfma_f32_16x16x32_f16(C8H(aw), C8H(bw), acc2[n2], 0, 0, 0);
    }
  }
  {
    _Float16* h2p = (_Float16*)(ls4 + 1088);   // row stride 72 f16 (9 f4)
    #pragma unroll
    for(int n2=0;n2<4;n2++)
      #pragma unroll
      for(int i=0;i<4;i++)
        h2p[(16*wv + 4*kb + i)*72 + 16*n2 + (l&15)] =
            (_Float16)fmaxf(acc2[n2][i], 0.f);
  }
  __syncthreads();   // B4: H2-MLP ready

  // tail: layers 3+4 (per-sample quad, i-paired fdot2)
  v2h hp3[8];
  {
    const uint4* hr = (const uint4*)(ls4 + 1088 + wid*9 + 2*q);
    uint4 d0 = hr[0], d1 = hr[1];
    hp3[0]=C2H(d0.x); hp3[1]=C2H(d0.y); hp3[2]=C2H(d0.z); hp3[3]=C2H(d0.w);
    hp3[4]=C2H(d1.x); hp3[5]=C2H(d1.y); hp3[6]=C2H(d1.z); hp3[7]=C2H(d1.w);
  }
  float x = ls[LMB4];
  #pragma unroll
  for(int g=0;g<4;g++){
    float a[8];
    #pragma unroll
    for(int j=0;j<8;j++) a[j]=0.f;
    #pragma unroll
    for(int ip=0;ip<8;ip++){
      const uint4* w3p = (const uint4*)(ls4 + M3HL + q*66 + ip*8 + 2*g);
      uint4 b0=w3p[0], b1=w3p[1];
      a[0]=FD2(C2H(b0.x),hp3[ip],a[0]); a[1]=FD2(C2H(b0.y),hp3[ip],a[1]);
      a[2]=FD2(C2H(b0.z),hp3[ip],a[2]); a[3]=FD2(C2H(b0.w),hp3[ip],a[3]);
      a[4]=FD2(C2H(b1.x),hp3[ip],a[4]); a[5]=FD2(C2H(b1.y),hp3[ip],a[5]);
      a[6]=FD2(C2H(b1.z),hp3[ip],a[6]); a[7]=FD2(C2H(b1.w),hp3[ip],a[7]);
    }
    #pragma unroll
    for(int j=0;j<8;j++) a[j] = bsum4(a[j]);
    #pragma unroll
    for(int j=0;j<8;j++)
      x += ls[LM4+8*g+j] * fmaxf(a[j] + ls[LMB3+8*g+j], 0.f);
  }

  if(q==0) out[b] = 1.0f/(1.0f + __expf(-x));
}

extern "C" void kernel_launch(void* const* d_in, const int* in_sizes, int n_in,
                              void* d_out, int out_size, void* d_ws, size_t ws_size,
                              hipStream_t stream){
  const int* userid    = (const int*)d_in[0];
  const int* itemid    = (const int*)d_in[1];
  const int* age       = (const int*)d_in[2];
  const int* gen       = (const int*)d_in[3];
  const int* occ       = (const int*)d_in[4];
  const int* item_kind = (const int*)d_in[5];
  const int* his_id    = (const int*)d_in[6];
  const int* his_kind  = (const int*)d_in[7];
  const float2* user_emb = (const float2*)d_in[8];
  const float2* item_emb = (const float2*)d_in[9];
  const float2* age_emb  = (const float2*)d_in[10];
  const float2* gen_emb  = (const float2*)d_in[11];
  const float2* occ_emb  = (const float2*)d_in[12];
  const float2* kind_emb = (const float2*)d_in[13];
  float* ws = (float*)d_ws;

  din_prep<<<(PREP_N+255)/256, 256, 0, stream>>>(
      (fp)d_in[14], (fp)d_in[15], (fp)d_in[16], (fp)d_in[17], (fp)d_in[18], (fp)d_in[19],
      (fp)d_in[20], (fp)d_in[21], (fp)d_in[22], (fp)d_in[23], (fp)d_in[24], (fp)d_in[25],
      (fp)d_in[26], (fp)d_in[27], ws);

  din_main<<<BATCH/SB, NTH, 0, stream>>>(
      userid, itemid, age, gen, occ, item_kind, his_id, his_kind,
      user_emb, item_emb, age_emb, gen_emb, occ_emb, kind_emb,
      ws, (float*)d_out);
}